// Round 1
// baseline (942.792 us; speedup 1.0000x reference)
//
#include <hip/hip_runtime.h>

#define N_NODES   50000
#define N_EDGES   800000
#define NUM_GRAPHS 64
#define D         128
#define SLOPE     0.01f

__device__ __forceinline__ float leaky(float v) { return v >= 0.f ? v : SLOPE * v; }

// ---------------- zero ----------------
__global__ void zero_kernel(int* __restrict__ p, int n) {
    int i = blockIdx.x * blockDim.x + threadIdx.x;
    if (i < n) p[i] = 0;
}

// ---------------- degree histogram (by col) ----------------
__global__ void hist_kernel(const int* __restrict__ col, int* __restrict__ hist, int E) {
    int e = blockIdx.x * blockDim.x + threadIdx.x;
    if (e < E) atomicAdd(&hist[col[e]], 1);
}

// ---------------- dinv = rsqrt(deg+1) ----------------
__global__ void dinv_kernel(const int* __restrict__ hist, float* __restrict__ dinv, int n) {
    int i = blockIdx.x * blockDim.x + threadIdx.x;
    if (i < n) dinv[i] = rsqrtf((float)hist[i] + 1.0f);
}

// ---------------- exclusive scan over hist -> start, cursor ----------------
__global__ __launch_bounds__(1024) void scan_kernel(const int* __restrict__ hist,
                                                    int* __restrict__ start,
                                                    int* __restrict__ cursor, int n) {
    __shared__ int tmp[1024];
    const int tid = threadIdx.x;
    int carry = 0;
    for (int base = 0; base < n; base += 1024) {
        int v = (base + tid < n) ? hist[base + tid] : 0;
        tmp[tid] = v;
        __syncthreads();
        for (int off = 1; off < 1024; off <<= 1) {
            int t = (tid >= off) ? tmp[tid - off] : 0;
            __syncthreads();
            tmp[tid] += t;
            __syncthreads();
        }
        int excl  = tmp[tid] - v;
        int total = tmp[1023];
        if (base + tid < n) {
            start[base + tid]  = carry + excl;
            cursor[base + tid] = carry + excl;
        }
        carry += total;
        __syncthreads();
    }
    if (tid == 0) start[n] = carry;
}

// ---------------- CSR build: scatter edges sorted by col ----------------
__global__ void build_kernel(const int* __restrict__ row, const int* __restrict__ col,
                             const float* __restrict__ dinv, int* __restrict__ cursor,
                             int* __restrict__ srcrow, float* __restrict__ coefs, int E) {
    int e = blockIdx.x * blockDim.x + threadIdx.x;
    if (e >= E) return;
    int r = row[e], c = col[e];
    int p = atomicAdd(&cursor[c], 1);
    srcrow[p] = r;
    coefs[p]  = dinv[r] * dinv[c];
}

// ---------------- f32 GEMM: C[M x 128] = A[M x 128] @ W[128 x 128], optional leaky ----------------
// block 256 threads, tile 64 rows x 128 cols, k-chunks of 32
__global__ __launch_bounds__(256) void gemm128(const float* __restrict__ A,
                                               const float* __restrict__ W,
                                               float* __restrict__ C, int M, int act) {
    __shared__ float As[64][36];    // pad 36 -> float4-aligned rows (144B)
    __shared__ float Ws[32][136];   // pad 136 -> float4-aligned rows (544B)
    const int tid = threadIdx.x;
    const int rg = tid >> 4;        // 0..15 (row group of 4)
    const int cg = tid & 15;        // 0..15 (col group: cols cg*4..+3 and cg*4+64..+67)
    const int rowBase = blockIdx.x * 64;

    float acc[4][8];
#pragma unroll
    for (int r = 0; r < 4; ++r)
#pragma unroll
        for (int j = 0; j < 8; ++j) acc[r][j] = 0.f;

    const int lr = tid >> 2;            // 0..63 A-load row
    const int lc = (tid & 3) * 8;       // 0,8,16,24
    const int wr = tid >> 3;            // 0..31 W-load row
    const int wc = (tid & 7) * 16;      // 0..112

    for (int kc = 0; kc < 128; kc += 32) {
        // stage A chunk (64 x 32)
        {
            int grow = rowBase + lr;
            float4 a0, a1;
            if (grow < M) {
                const float4* src = reinterpret_cast<const float4*>(A + (size_t)grow * D + kc + lc);
                a0 = src[0]; a1 = src[1];
            } else {
                a0 = make_float4(0.f, 0.f, 0.f, 0.f); a1 = a0;
            }
            *reinterpret_cast<float4*>(&As[lr][lc])     = a0;
            *reinterpret_cast<float4*>(&As[lr][lc + 4]) = a1;
        }
        // stage W chunk (32 x 128)
        {
            const float4* src = reinterpret_cast<const float4*>(W + (size_t)(kc + wr) * D + wc);
#pragma unroll
            for (int i = 0; i < 4; ++i)
                *reinterpret_cast<float4*>(&Ws[wr][wc + 4 * i]) = src[i];
        }
        __syncthreads();
#pragma unroll
        for (int k = 0; k < 32; ++k) {
            float xv0 = As[rg * 4 + 0][k];
            float xv1 = As[rg * 4 + 1][k];
            float xv2 = As[rg * 4 + 2][k];
            float xv3 = As[rg * 4 + 3][k];
            float4 w0 = *reinterpret_cast<const float4*>(&Ws[k][cg * 4]);
            float4 w1 = *reinterpret_cast<const float4*>(&Ws[k][cg * 4 + 64]);
            acc[0][0] += xv0 * w0.x; acc[0][1] += xv0 * w0.y; acc[0][2] += xv0 * w0.z; acc[0][3] += xv0 * w0.w;
            acc[0][4] += xv0 * w1.x; acc[0][5] += xv0 * w1.y; acc[0][6] += xv0 * w1.z; acc[0][7] += xv0 * w1.w;
            acc[1][0] += xv1 * w0.x; acc[1][1] += xv1 * w0.y; acc[1][2] += xv1 * w0.z; acc[1][3] += xv1 * w0.w;
            acc[1][4] += xv1 * w1.x; acc[1][5] += xv1 * w1.y; acc[1][6] += xv1 * w1.z; acc[1][7] += xv1 * w1.w;
            acc[2][0] += xv2 * w0.x; acc[2][1] += xv2 * w0.y; acc[2][2] += xv2 * w0.z; acc[2][3] += xv2 * w0.w;
            acc[2][4] += xv2 * w1.x; acc[2][5] += xv2 * w1.y; acc[2][6] += xv2 * w1.z; acc[2][7] += xv2 * w1.w;
            acc[3][0] += xv3 * w0.x; acc[3][1] += xv3 * w0.y; acc[3][2] += xv3 * w0.z; acc[3][3] += xv3 * w0.w;
            acc[3][4] += xv3 * w1.x; acc[3][5] += xv3 * w1.y; acc[3][6] += xv3 * w1.z; acc[3][7] += xv3 * w1.w;
        }
        __syncthreads();
    }

#pragma unroll
    for (int r = 0; r < 4; ++r) {
        int grow = rowBase + rg * 4 + r;
        if (grow < M) {
            float4 o0 = make_float4(acc[r][0], acc[r][1], acc[r][2], acc[r][3]);
            float4 o1 = make_float4(acc[r][4], acc[r][5], acc[r][6], acc[r][7]);
            if (act) {
                o0.x = leaky(o0.x); o0.y = leaky(o0.y); o0.z = leaky(o0.z); o0.w = leaky(o0.w);
                o1.x = leaky(o1.x); o1.y = leaky(o1.y); o1.z = leaky(o1.z); o1.w = leaky(o1.w);
            }
            *reinterpret_cast<float4*>(&C[(size_t)grow * D + cg * 4])      = o0;
            *reinterpret_cast<float4*>(&C[(size_t)grow * D + cg * 4 + 64]) = o1;
        }
    }
}

// ---------------- aggregation + self-loop + leaky (one wave per node) ----------------
__global__ __launch_bounds__(256) void agg_combine(const float* __restrict__ h,
                                                   const int* __restrict__ srcrow,
                                                   const float* __restrict__ coefs,
                                                   const int* __restrict__ start,
                                                   const float* __restrict__ dinv,
                                                   float* __restrict__ out, int n) {
    int wave = (int)((blockIdx.x * blockDim.x + threadIdx.x) >> 6);
    int lane = threadIdx.x & 63;
    if (wave >= n) return;
    int s = start[wave], e = start[wave + 1];
    const int f = lane * 2;
    float2 acc = make_float2(0.f, 0.f);
    for (int p = s; p < e; ++p) {
        int r = srcrow[p];
        float cf = coefs[p];
        float2 hv = *reinterpret_cast<const float2*>(h + (size_t)r * D + f);
        acc.x += hv.x * cf;
        acc.y += hv.y * cf;
    }
    float dw = dinv[wave]; dw *= dw;
    float2 hs = *reinterpret_cast<const float2*>(h + (size_t)wave * D + f);
    acc.x = leaky(acc.x + hs.x * dw);
    acc.y = leaky(acc.y + hs.y * dw);
    *reinterpret_cast<float2*>(out + (size_t)wave * D + f) = acc;
}

// ---------------- fc2 (128->1) + pooled sums (one wave per node) ----------------
__global__ __launch_bounds__(256) void fc2_pool(const float* __restrict__ y,
                                                const float* __restrict__ w,
                                                const int* __restrict__ batch,
                                                float* __restrict__ sums,
                                                float* __restrict__ cnts, int n) {
    int wave = (int)((blockIdx.x * blockDim.x + threadIdx.x) >> 6);
    int lane = threadIdx.x & 63;
    if (wave >= n) return;
    float2 yv = *reinterpret_cast<const float2*>(y + (size_t)wave * D + lane * 2);
    float2 wv = *reinterpret_cast<const float2*>(w + lane * 2);
    float part = yv.x * wv.x + yv.y * wv.y;
#pragma unroll
    for (int off = 32; off > 0; off >>= 1) part += __shfl_down(part, off, 64);
    if (lane == 0) {
        float s = leaky(part);
        int g = batch[wave];
        atomicAdd(&sums[g], s);
        atomicAdd(&cnts[g], 1.0f);
    }
}

// ---------------- final: out = sums / max(cnts,1) ----------------
__global__ void final_kernel(const float* __restrict__ sums, const float* __restrict__ cnts,
                             float* __restrict__ out) {
    int g = threadIdx.x;
    if (g < NUM_GRAPHS) out[g] = sums[g] / fmaxf(cnts[g], 1.0f);
}

extern "C" void kernel_launch(void* const* d_in, const int* in_sizes, int n_in,
                              void* d_out, int out_size, void* d_ws, size_t ws_size,
                              hipStream_t stream) {
    const float* x    = (const float*)d_in[0];
    const int*   eidx = (const int*)d_in[1];     // [2, E]: row = eidx[0:E), col = eidx[E:2E)
    const int*   batch= (const int*)d_in[2];
    const float* W0   = (const float*)d_in[3];
    const float* W1   = (const float*)d_in[4];
    const float* W2   = (const float*)d_in[5];
    const float* Wfc1 = (const float*)d_in[6];
    const float* Wfc2 = (const float*)d_in[7];
    float* out = (float*)d_out;

    const int* erow = eidx;
    const int* ecol = eidx + N_EDGES;

    // workspace layout (word offsets, 64-word aligned)
    char* ws = (char*)d_ws;
    float* sums   = (float*)(ws);                         // 64
    float* cnts   = (float*)(ws + 64 * 4);                // 64
    int*   hist   = (int*)  (ws + 128 * 4);               // 50000
    int*   start  = (int*)  (ws + (size_t)50176 * 4);     // 50001
    int*   cursor = (int*)  (ws + (size_t)100224 * 4);    // 50000
    float* dinv   = (float*)(ws + (size_t)150272 * 4);    // 50000
    int*   srcrow = (int*)  (ws + (size_t)200320 * 4);    // 800000
    float* coefs  = (float*)(ws + (size_t)1000320 * 4);   // 800000
    float* bufA   = (float*)(ws + (size_t)1800320 * 4);   // 6,400,000
    float* bufB   = (float*)(ws + (size_t)8200320 * 4);   // 6,400,000

    const int ZN = 50128;  // sums + cnts + hist (contiguous)
    zero_kernel<<<(ZN + 255) / 256, 256, 0, stream>>>((int*)ws, ZN);

    hist_kernel<<<(N_EDGES + 255) / 256, 256, 0, stream>>>(ecol, hist, N_EDGES);
    dinv_kernel<<<(N_NODES + 255) / 256, 256, 0, stream>>>(hist, dinv, N_NODES);
    scan_kernel<<<1, 1024, 0, stream>>>(hist, start, cursor, N_NODES);
    build_kernel<<<(N_EDGES + 255) / 256, 256, 0, stream>>>(erow, ecol, dinv, cursor,
                                                            srcrow, coefs, N_EDGES);

    const int GEMM_GRID = (N_NODES + 63) / 64;   // 782
    const int AGG_GRID  = (N_NODES + 3) / 4;     // 12500 (4 waves/block)

    // layer 0: h = x @ W0 -> bufA; agg(bufA) -> bufB
    gemm128<<<GEMM_GRID, 256, 0, stream>>>(x, W0, bufA, N_NODES, 0);
    agg_combine<<<AGG_GRID, 256, 0, stream>>>(bufA, srcrow, coefs, start, dinv, bufB, N_NODES);
    // layer 1
    gemm128<<<GEMM_GRID, 256, 0, stream>>>(bufB, W1, bufA, N_NODES, 0);
    agg_combine<<<AGG_GRID, 256, 0, stream>>>(bufA, srcrow, coefs, start, dinv, bufB, N_NODES);
    // layer 2
    gemm128<<<GEMM_GRID, 256, 0, stream>>>(bufB, W2, bufA, N_NODES, 0);
    agg_combine<<<AGG_GRID, 256, 0, stream>>>(bufA, srcrow, coefs, start, dinv, bufB, N_NODES);
    // fc1 (+leaky)
    gemm128<<<GEMM_GRID, 256, 0, stream>>>(bufB, Wfc1, bufA, N_NODES, 1);
    // fc2 + pool
    fc2_pool<<<AGG_GRID, 256, 0, stream>>>(bufA, Wfc2, batch, sums, cnts, N_NODES);
    final_kernel<<<1, 64, 0, stream>>>(sums, cnts, out);
}

// Round 3
// 776.165 us; speedup vs baseline: 1.2147x; 1.2147x over previous
//
#include <hip/hip_runtime.h>

#define N_NODES   50000
#define N_EDGES   800000
#define NUM_GRAPHS 64
#define D         128
#define SLOPE     0.01

__device__ __forceinline__ double dleaky(double v) { return v >= 0.0 ? v : SLOPE * v; }

// ---------------- zero ----------------
__global__ void zero_kernel(int* __restrict__ p, int n) {
    int i = blockIdx.x * blockDim.x + threadIdx.x;
    if (i < n) p[i] = 0;
}

// ---------------- degree histogram (by col) ----------------
__global__ void hist_kernel(const int* __restrict__ col, int* __restrict__ hist, int E) {
    int e = blockIdx.x * blockDim.x + threadIdx.x;
    if (e < E) atomicAdd(&hist[col[e]], 1);
}

// ---------------- dinv = 1/sqrt(deg+1) in double ----------------
__global__ void dinv_kernel(const int* __restrict__ hist, double* __restrict__ dinvd, int n) {
    int i = blockIdx.x * blockDim.x + threadIdx.x;
    if (i < n) dinvd[i] = 1.0 / sqrt((double)hist[i] + 1.0);
}

// ---------------- multi-block exclusive scan (3 kernels) ----------------
__global__ __launch_bounds__(256) void scan1(const int* __restrict__ hist,
                                             int* __restrict__ start,
                                             int* __restrict__ bsum, int n) {
    __shared__ int tmp[256];
    const int tid = threadIdx.x;
    int base = blockIdx.x * 1024 + tid * 4;
    int v[4]; int s = 0;
#pragma unroll
    for (int i = 0; i < 4; ++i) { int idx = base + i; v[i] = (idx < n) ? hist[idx] : 0; s += v[i]; }
    tmp[tid] = s;
    __syncthreads();
    for (int off = 1; off < 256; off <<= 1) {
        int t = (tid >= off) ? tmp[tid - off] : 0;
        __syncthreads();
        tmp[tid] += t;
        __syncthreads();
    }
    int run = tmp[tid] - s;
    if (tid == 255) bsum[blockIdx.x] = tmp[255];
#pragma unroll
    for (int i = 0; i < 4; ++i) { int idx = base + i; if (idx < n) start[idx] = run; run += v[i]; }
}

__global__ __launch_bounds__(256) void scan2(int* __restrict__ bsum, int nb,
                                             int* __restrict__ start, int n) {
    __shared__ int tmp[256];
    const int tid = threadIdx.x;
    int v = (tid < nb) ? bsum[tid] : 0;
    tmp[tid] = v;
    __syncthreads();
    for (int off = 1; off < 256; off <<= 1) {
        int t = (tid >= off) ? tmp[tid - off] : 0;
        __syncthreads();
        tmp[tid] += t;
        __syncthreads();
    }
    if (tid < nb) bsum[tid] = tmp[tid] - v;
    if (tid == 255) start[n] = tmp[255];
}

__global__ __launch_bounds__(256) void scan3(int* __restrict__ start, int* __restrict__ cursor,
                                             const int* __restrict__ bsum, int n) {
    int off = bsum[blockIdx.x];
    int base = blockIdx.x * 1024 + threadIdx.x * 4;
#pragma unroll
    for (int i = 0; i < 4; ++i) {
        int j = base + i;
        if (j < n) { int v = start[j] + off; start[j] = v; cursor[j] = v; }
    }
}

// ---------------- CSR build: scatter source rows, sorted by col ----------------
__global__ void build_kernel(const int* __restrict__ row, const int* __restrict__ col,
                             int* __restrict__ cursor, int* __restrict__ srcrow, int E) {
    int e = blockIdx.x * blockDim.x + threadIdx.x;
    if (e >= E) return;
    int p = atomicAdd(&cursor[col[e]], 1);
    srcrow[p] = row[e];
}

// ---------------- GEMM: C[M x 128] = A[M x 128] @ W[128 x 128], f64 accumulate ----------------
// block 256, tile 64 rows x 128 cols, k-chunks of 32; LDS staged as double.
__global__ __launch_bounds__(256) void gemm128_d(const float* __restrict__ A,
                                                 const float* __restrict__ W,
                                                 float* __restrict__ C, int M, int act) {
    __shared__ double As[64][34];    // stride 272B: 16B-aligned rows, conflict-benign
    __shared__ double Ws[32][132];   // stride 1056B
    const int tid = threadIdx.x;
    const int rg = tid >> 4;        // 0..15
    const int cg = tid & 15;        // 0..15
    const int rowBase = blockIdx.x * 64;

    double acc[4][8];
#pragma unroll
    for (int r = 0; r < 4; ++r)
#pragma unroll
        for (int j = 0; j < 8; ++j) acc[r][j] = 0.0;

    const int lr = tid >> 2;            // 0..63
    const int lc = (tid & 3) * 8;       // 0,8,16,24
    const int wr = tid >> 3;            // 0..31
    const int wc = (tid & 7) * 16;      // 0..112

    for (int kc = 0; kc < 128; kc += 32) {
        {
            int grow = rowBase + lr;
            float4 a0 = make_float4(0.f, 0.f, 0.f, 0.f), a1 = a0;
            if (grow < M) {
                const float4* src = reinterpret_cast<const float4*>(A + (size_t)grow * D + kc + lc);
                a0 = src[0]; a1 = src[1];
            }
            *reinterpret_cast<double2*>(&As[lr][lc + 0]) = make_double2((double)a0.x, (double)a0.y);
            *reinterpret_cast<double2*>(&As[lr][lc + 2]) = make_double2((double)a0.z, (double)a0.w);
            *reinterpret_cast<double2*>(&As[lr][lc + 4]) = make_double2((double)a1.x, (double)a1.y);
            *reinterpret_cast<double2*>(&As[lr][lc + 6]) = make_double2((double)a1.z, (double)a1.w);
        }
        {
            const float4* src = reinterpret_cast<const float4*>(W + (size_t)(kc + wr) * D + wc);
#pragma unroll
            for (int i = 0; i < 4; ++i) {
                float4 wv = src[i];
                *reinterpret_cast<double2*>(&Ws[wr][wc + 4 * i + 0]) = make_double2((double)wv.x, (double)wv.y);
                *reinterpret_cast<double2*>(&Ws[wr][wc + 4 * i + 2]) = make_double2((double)wv.z, (double)wv.w);
            }
        }
        __syncthreads();
#pragma unroll
        for (int k = 0; k < 32; ++k) {
            double xv0 = As[rg * 4 + 0][k];
            double xv1 = As[rg * 4 + 1][k];
            double xv2 = As[rg * 4 + 2][k];
            double xv3 = As[rg * 4 + 3][k];
            double2 w00 = *reinterpret_cast<const double2*>(&Ws[k][cg * 4 + 0]);
            double2 w01 = *reinterpret_cast<const double2*>(&Ws[k][cg * 4 + 2]);
            double2 w10 = *reinterpret_cast<const double2*>(&Ws[k][cg * 4 + 64]);
            double2 w11 = *reinterpret_cast<const double2*>(&Ws[k][cg * 4 + 66]);
            acc[0][0] = fma(xv0, w00.x, acc[0][0]); acc[0][1] = fma(xv0, w00.y, acc[0][1]);
            acc[0][2] = fma(xv0, w01.x, acc[0][2]); acc[0][3] = fma(xv0, w01.y, acc[0][3]);
            acc[0][4] = fma(xv0, w10.x, acc[0][4]); acc[0][5] = fma(xv0, w10.y, acc[0][5]);
            acc[0][6] = fma(xv0, w11.x, acc[0][6]); acc[0][7] = fma(xv0, w11.y, acc[0][7]);
            acc[1][0] = fma(xv1, w00.x, acc[1][0]); acc[1][1] = fma(xv1, w00.y, acc[1][1]);
            acc[1][2] = fma(xv1, w01.x, acc[1][2]); acc[1][3] = fma(xv1, w01.y, acc[1][3]);
            acc[1][4] = fma(xv1, w10.x, acc[1][4]); acc[1][5] = fma(xv1, w10.y, acc[1][5]);
            acc[1][6] = fma(xv1, w11.x, acc[1][6]); acc[1][7] = fma(xv1, w11.y, acc[1][7]);
            acc[2][0] = fma(xv2, w00.x, acc[2][0]); acc[2][1] = fma(xv2, w00.y, acc[2][1]);
            acc[2][2] = fma(xv2, w01.x, acc[2][2]); acc[2][3] = fma(xv2, w01.y, acc[2][3]);
            acc[2][4] = fma(xv2, w10.x, acc[2][4]); acc[2][5] = fma(xv2, w10.y, acc[2][5]);
            acc[2][6] = fma(xv2, w11.x, acc[2][6]); acc[2][7] = fma(xv2, w11.y, acc[2][7]);
            acc[3][0] = fma(xv3, w00.x, acc[3][0]); acc[3][1] = fma(xv3, w00.y, acc[3][1]);
            acc[3][2] = fma(xv3, w01.x, acc[3][2]); acc[3][3] = fma(xv3, w01.y, acc[3][3]);
            acc[3][4] = fma(xv3, w10.x, acc[3][4]); acc[3][5] = fma(xv3, w10.y, acc[3][5]);
            acc[3][6] = fma(xv3, w11.x, acc[3][6]); acc[3][7] = fma(xv3, w11.y, acc[3][7]);
        }
        __syncthreads();
    }

#pragma unroll
    for (int r = 0; r < 4; ++r) {
        int grow = rowBase + rg * 4 + r;
        if (grow < M) {
            double v[8];
#pragma unroll
            for (int j = 0; j < 8; ++j) v[j] = act ? dleaky(acc[r][j]) : acc[r][j];
            float4 o0 = make_float4((float)v[0], (float)v[1], (float)v[2], (float)v[3]);
            float4 o1 = make_float4((float)v[4], (float)v[5], (float)v[6], (float)v[7]);
            *reinterpret_cast<float4*>(&C[(size_t)grow * D + cg * 4])      = o0;
            *reinterpret_cast<float4*>(&C[(size_t)grow * D + cg * 4 + 64]) = o1;
        }
    }
}

// ---------------- aggregation + self-loop + leaky, f64 accumulate (one wave per node) ----------------
__global__ __launch_bounds__(256) void agg_d(const float* __restrict__ h,
                                             const int* __restrict__ srcrow,
                                             const int* __restrict__ start,
                                             const double* __restrict__ dinvd,
                                             float* __restrict__ out, int n) {
    int node = (int)((blockIdx.x * blockDim.x + threadIdx.x) >> 6);
    int lane = threadIdx.x & 63;
    if (node >= n) return;
    int s = start[node], e = start[node + 1];
    double dn = dinvd[node];
    const int f = lane * 2;
    double ax = 0.0, ay = 0.0;
    for (int p = s; p < e; ++p) {
        int r = srcrow[p];
        double cf = dinvd[r] * dn;
        float2 hv = *reinterpret_cast<const float2*>(h + (size_t)r * D + f);
        ax = fma((double)hv.x, cf, ax);
        ay = fma((double)hv.y, cf, ay);
    }
    double dw = dn * dn;
    float2 hs = *reinterpret_cast<const float2*>(h + (size_t)node * D + f);
    ax = dleaky(ax + (double)hs.x * dw);
    ay = dleaky(ay + (double)hs.y * dw);
    *reinterpret_cast<float2*>(out + (size_t)node * D + f) =
        make_float2((float)ax, (float)ay);
}

// ---------------- fc2 (128->1): per-node scalar, f64 dot (one wave per node) ----------------
__global__ __launch_bounds__(256) void fc2_d(const float* __restrict__ y,
                                             const float* __restrict__ w,
                                             double* __restrict__ s, int n) {
    int node = (int)((blockIdx.x * blockDim.x + threadIdx.x) >> 6);
    int lane = threadIdx.x & 63;
    if (node >= n) return;
    float2 yv = *reinterpret_cast<const float2*>(y + (size_t)node * D + lane * 2);
    float2 wv = *reinterpret_cast<const float2*>(w + lane * 2);
    double part = (double)yv.x * (double)wv.x + (double)yv.y * (double)wv.y;
#pragma unroll
    for (int off = 32; off > 0; off >>= 1) part += __shfl_down(part, off, 64);
    if (lane == 0) s[node] = dleaky(part);
}

// ---------------- pool: one block per graph, f64 tree reduce, no atomics ----------------
__global__ __launch_bounds__(256) void pool_d(const double* __restrict__ s,
                                              const int* __restrict__ batch,
                                              float* __restrict__ out, int n) {
    __shared__ double lsum[256];
    __shared__ int    lcnt[256];
    const int g = blockIdx.x;
    const int tid = threadIdx.x;
    double sum = 0.0; int cnt = 0;
    for (int i = tid; i < n; i += 256) {
        if (batch[i] == g) { sum += s[i]; cnt++; }
    }
    lsum[tid] = sum; lcnt[tid] = cnt;
    __syncthreads();
    for (int off = 128; off > 0; off >>= 1) {
        if (tid < off) { lsum[tid] += lsum[tid + off]; lcnt[tid] += lcnt[tid + off]; }
        __syncthreads();
    }
    if (tid == 0) out[g] = (float)(lsum[0] / (double)(lcnt[0] > 0 ? lcnt[0] : 1));
}

extern "C" void kernel_launch(void* const* d_in, const int* in_sizes, int n_in,
                              void* d_out, int out_size, void* d_ws, size_t ws_size,
                              hipStream_t stream) {
    const float* x    = (const float*)d_in[0];
    const int*   eidx = (const int*)d_in[1];
    const int*   batch= (const int*)d_in[2];
    const float* W0   = (const float*)d_in[3];
    const float* W1   = (const float*)d_in[4];
    const float* W2   = (const float*)d_in[5];
    const float* Wfc1 = (const float*)d_in[6];
    const float* Wfc2 = (const float*)d_in[7];
    float* out = (float*)d_out;

    const int* erow = eidx;
    const int* ecol = eidx + N_EDGES;

    // workspace layout (byte offsets, 256-aligned)
    char* ws = (char*)d_ws;
    int*    hist   = (int*)   (ws + 0);                 // 50000 ints
    int*    start  = (int*)   (ws + 200064);            // 50001 ints
    int*    cursor = (int*)   (ws + 400384);            // 50000 ints
    int*    bsum   = (int*)   (ws + 600448);            // 64 ints
    double* dinvd  = (double*)(ws + 600704);            // 50000 doubles
    int*    srcrow = (int*)   (ws + 1000704);           // 800000 ints
    double* svec   = (double*)(ws + 4200704);           // 50000 doubles
    float*  bufA   = (float*) (ws + 4600832);           // 6,400,000 floats
    float*  bufB   = (float*) (ws + 30200832);          // 6,400,000 floats (end ~55.8 MB)

    zero_kernel<<<(N_NODES + 255) / 256, 256, 0, stream>>>(hist, N_NODES);
    hist_kernel<<<(N_EDGES + 255) / 256, 256, 0, stream>>>(ecol, hist, N_EDGES);
    dinv_kernel<<<(N_NODES + 255) / 256, 256, 0, stream>>>(hist, dinvd, N_NODES);

    const int NB = (N_NODES + 1023) / 1024;  // 49
    scan1<<<NB, 256, 0, stream>>>(hist, start, bsum, N_NODES);
    scan2<<<1, 256, 0, stream>>>(bsum, NB, start, N_NODES);
    scan3<<<NB, 256, 0, stream>>>(start, cursor, bsum, N_NODES);

    build_kernel<<<(N_EDGES + 255) / 256, 256, 0, stream>>>(erow, ecol, cursor, srcrow, N_EDGES);

    const int GEMM_GRID = (N_NODES + 63) / 64;   // 782
    const int AGG_GRID  = (N_NODES + 3) / 4;     // 12500

    gemm128_d<<<GEMM_GRID, 256, 0, stream>>>(x, W0, bufA, N_NODES, 0);
    agg_d<<<AGG_GRID, 256, 0, stream>>>(bufA, srcrow, start, dinvd, bufB, N_NODES);
    gemm128_d<<<GEMM_GRID, 256, 0, stream>>>(bufB, W1, bufA, N_NODES, 0);
    agg_d<<<AGG_GRID, 256, 0, stream>>>(bufA, srcrow, start, dinvd, bufB, N_NODES);
    gemm128_d<<<GEMM_GRID, 256, 0, stream>>>(bufB, W2, bufA, N_NODES, 0);
    agg_d<<<AGG_GRID, 256, 0, stream>>>(bufA, srcrow, start, dinvd, bufB, N_NODES);
    gemm128_d<<<GEMM_GRID, 256, 0, stream>>>(bufB, Wfc1, bufA, N_NODES, 1);

    fc2_d<<<AGG_GRID, 256, 0, stream>>>(bufA, Wfc2, svec, N_NODES);
    pool_d<<<NUM_GRAPHS, 256, 0, stream>>>(svec, batch, out, N_NODES);
}

// Round 4
// 607.469 us; speedup vs baseline: 1.5520x; 1.2777x over previous
//
#include <hip/hip_runtime.h>

#define N_NODES   50000
#define N_EDGES   800000
#define NUM_GRAPHS 64
#define D         128
#define SLOPE     0.01

__device__ __forceinline__ double dleaky(double v) { return v >= 0.0 ? v : SLOPE * v; }

// ---------------- zero ----------------
__global__ void zero_kernel(int* __restrict__ p, int n) {
    int i = blockIdx.x * blockDim.x + threadIdx.x;
    if (i < n) p[i] = 0;
}

// ---------------- degree histogram (by col) ----------------
__global__ void hist_kernel(const int* __restrict__ col, int* __restrict__ hist, int E) {
    int e = blockIdx.x * blockDim.x + threadIdx.x;
    if (e < E) atomicAdd(&hist[col[e]], 1);
}

// ---------------- dinv = 1/sqrt(deg+1) in double ----------------
__global__ void dinv_kernel(const int* __restrict__ hist, double* __restrict__ dinvd, int n) {
    int i = blockIdx.x * blockDim.x + threadIdx.x;
    if (i < n) dinvd[i] = 1.0 / sqrt((double)hist[i] + 1.0);
}

// ---------------- multi-block exclusive scan (3 kernels) ----------------
__global__ __launch_bounds__(256) void scan1(const int* __restrict__ hist,
                                             int* __restrict__ start,
                                             int* __restrict__ bsum, int n) {
    __shared__ int tmp[256];
    const int tid = threadIdx.x;
    int base = blockIdx.x * 1024 + tid * 4;
    int v[4]; int s = 0;
#pragma unroll
    for (int i = 0; i < 4; ++i) { int idx = base + i; v[i] = (idx < n) ? hist[idx] : 0; s += v[i]; }
    tmp[tid] = s;
    __syncthreads();
    for (int off = 1; off < 256; off <<= 1) {
        int t = (tid >= off) ? tmp[tid - off] : 0;
        __syncthreads();
        tmp[tid] += t;
        __syncthreads();
    }
    int run = tmp[tid] - s;
    if (tid == 255) bsum[blockIdx.x] = tmp[255];
#pragma unroll
    for (int i = 0; i < 4; ++i) { int idx = base + i; if (idx < n) start[idx] = run; run += v[i]; }
}

__global__ __launch_bounds__(256) void scan2(int* __restrict__ bsum, int nb,
                                             int* __restrict__ start, int n) {
    __shared__ int tmp[256];
    const int tid = threadIdx.x;
    int v = (tid < nb) ? bsum[tid] : 0;
    tmp[tid] = v;
    __syncthreads();
    for (int off = 1; off < 256; off <<= 1) {
        int t = (tid >= off) ? tmp[tid - off] : 0;
        __syncthreads();
        tmp[tid] += t;
        __syncthreads();
    }
    if (tid < nb) bsum[tid] = tmp[tid] - v;
    if (tid == 255) start[n] = tmp[255];
}

__global__ __launch_bounds__(256) void scan3(int* __restrict__ start, int* __restrict__ cursor,
                                             const int* __restrict__ bsum, int n) {
    int off = bsum[blockIdx.x];
    int base = blockIdx.x * 1024 + threadIdx.x * 4;
#pragma unroll
    for (int i = 0; i < 4; ++i) {
        int j = base + i;
        if (j < n) { int v = start[j] + off; start[j] = v; cursor[j] = v; }
    }
}

// ---------------- CSR build: scatter source rows, sorted by col ----------------
__global__ void build_kernel(const int* __restrict__ row, const int* __restrict__ col,
                             int* __restrict__ cursor, int* __restrict__ srcrow, int E) {
    int e = blockIdx.x * blockDim.x + threadIdx.x;
    if (e >= E) return;
    int p = atomicAdd(&cursor[col[e]], 1);
    srcrow[p] = row[e];
}

// ---------------- GEMM: C[M x 128] = A[M x 128] @ W[128 x 128], f64 accumulate ----------------
__global__ __launch_bounds__(256) void gemm128_d(const float* __restrict__ A,
                                                 const float* __restrict__ W,
                                                 float* __restrict__ C, int M, int act) {
    __shared__ double As[64][34];
    __shared__ double Ws[32][132];
    const int tid = threadIdx.x;
    const int rg = tid >> 4;
    const int cg = tid & 15;
    const int rowBase = blockIdx.x * 64;

    double acc[4][8];
#pragma unroll
    for (int r = 0; r < 4; ++r)
#pragma unroll
        for (int j = 0; j < 8; ++j) acc[r][j] = 0.0;

    const int lr = tid >> 2;
    const int lc = (tid & 3) * 8;
    const int wr = tid >> 3;
    const int wc = (tid & 7) * 16;

    for (int kc = 0; kc < 128; kc += 32) {
        {
            int grow = rowBase + lr;
            float4 a0 = make_float4(0.f, 0.f, 0.f, 0.f), a1 = a0;
            if (grow < M) {
                const float4* src = reinterpret_cast<const float4*>(A + (size_t)grow * D + kc + lc);
                a0 = src[0]; a1 = src[1];
            }
            *reinterpret_cast<double2*>(&As[lr][lc + 0]) = make_double2((double)a0.x, (double)a0.y);
            *reinterpret_cast<double2*>(&As[lr][lc + 2]) = make_double2((double)a0.z, (double)a0.w);
            *reinterpret_cast<double2*>(&As[lr][lc + 4]) = make_double2((double)a1.x, (double)a1.y);
            *reinterpret_cast<double2*>(&As[lr][lc + 6]) = make_double2((double)a1.z, (double)a1.w);
        }
        {
            const float4* src = reinterpret_cast<const float4*>(W + (size_t)(kc + wr) * D + wc);
#pragma unroll
            for (int i = 0; i < 4; ++i) {
                float4 wv = src[i];
                *reinterpret_cast<double2*>(&Ws[wr][wc + 4 * i + 0]) = make_double2((double)wv.x, (double)wv.y);
                *reinterpret_cast<double2*>(&Ws[wr][wc + 4 * i + 2]) = make_double2((double)wv.z, (double)wv.w);
            }
        }
        __syncthreads();
#pragma unroll
        for (int k = 0; k < 32; ++k) {
            double xv0 = As[rg * 4 + 0][k];
            double xv1 = As[rg * 4 + 1][k];
            double xv2 = As[rg * 4 + 2][k];
            double xv3 = As[rg * 4 + 3][k];
            double2 w00 = *reinterpret_cast<const double2*>(&Ws[k][cg * 4 + 0]);
            double2 w01 = *reinterpret_cast<const double2*>(&Ws[k][cg * 4 + 2]);
            double2 w10 = *reinterpret_cast<const double2*>(&Ws[k][cg * 4 + 64]);
            double2 w11 = *reinterpret_cast<const double2*>(&Ws[k][cg * 4 + 66]);
            acc[0][0] = fma(xv0, w00.x, acc[0][0]); acc[0][1] = fma(xv0, w00.y, acc[0][1]);
            acc[0][2] = fma(xv0, w01.x, acc[0][2]); acc[0][3] = fma(xv0, w01.y, acc[0][3]);
            acc[0][4] = fma(xv0, w10.x, acc[0][4]); acc[0][5] = fma(xv0, w10.y, acc[0][5]);
            acc[0][6] = fma(xv0, w11.x, acc[0][6]); acc[0][7] = fma(xv0, w11.y, acc[0][7]);
            acc[1][0] = fma(xv1, w00.x, acc[1][0]); acc[1][1] = fma(xv1, w00.y, acc[1][1]);
            acc[1][2] = fma(xv1, w01.x, acc[1][2]); acc[1][3] = fma(xv1, w01.y, acc[1][3]);
            acc[1][4] = fma(xv1, w10.x, acc[1][4]); acc[1][5] = fma(xv1, w10.y, acc[1][5]);
            acc[1][6] = fma(xv1, w11.x, acc[1][6]); acc[1][7] = fma(xv1, w11.y, acc[1][7]);
            acc[2][0] = fma(xv2, w00.x, acc[2][0]); acc[2][1] = fma(xv2, w00.y, acc[2][1]);
            acc[2][2] = fma(xv2, w01.x, acc[2][2]); acc[2][3] = fma(xv2, w01.y, acc[2][3]);
            acc[2][4] = fma(xv2, w10.x, acc[2][4]); acc[2][5] = fma(xv2, w10.y, acc[2][5]);
            acc[2][6] = fma(xv2, w11.x, acc[2][6]); acc[2][7] = fma(xv2, w11.y, acc[2][7]);
            acc[3][0] = fma(xv3, w00.x, acc[3][0]); acc[3][1] = fma(xv3, w00.y, acc[3][1]);
            acc[3][2] = fma(xv3, w01.x, acc[3][2]); acc[3][3] = fma(xv3, w01.y, acc[3][3]);
            acc[3][4] = fma(xv3, w10.x, acc[3][4]); acc[3][5] = fma(xv3, w10.y, acc[3][5]);
            acc[3][6] = fma(xv3, w11.x, acc[3][6]); acc[3][7] = fma(xv3, w11.y, acc[3][7]);
        }
        __syncthreads();
    }

#pragma unroll
    for (int r = 0; r < 4; ++r) {
        int grow = rowBase + rg * 4 + r;
        if (grow < M) {
            double v[8];
#pragma unroll
            for (int j = 0; j < 8; ++j) v[j] = act ? dleaky(acc[r][j]) : acc[r][j];
            float4 o0 = make_float4((float)v[0], (float)v[1], (float)v[2], (float)v[3]);
            float4 o1 = make_float4((float)v[4], (float)v[5], (float)v[6], (float)v[7]);
            *reinterpret_cast<float4*>(&C[(size_t)grow * D + cg * 4])      = o0;
            *reinterpret_cast<float4*>(&C[(size_t)grow * D + cg * 4 + 64]) = o1;
        }
    }
}

// ---------------- aggregation + self-loop + leaky, f64 accumulate ----------------
// one wave per node; 4-deep MLP unroll on the edge gather
__global__ __launch_bounds__(256) void agg_d(const float* __restrict__ h,
                                             const int* __restrict__ srcrow,
                                             const int* __restrict__ start,
                                             const double* __restrict__ dinvd,
                                             float* __restrict__ out, int n) {
    int node = (int)((blockIdx.x * blockDim.x + threadIdx.x) >> 6);
    int lane = threadIdx.x & 63;
    if (node >= n) return;
    int s = start[node], e = start[node + 1];
    double dn = dinvd[node];
    const int f = lane * 2;
    double ax = 0.0, ay = 0.0;
    int p = s;
    for (; p + 4 <= e; p += 4) {
        // batch the independent loads: indices -> coefficients -> 4 h-rows in flight
        int r0 = srcrow[p + 0];
        int r1 = srcrow[p + 1];
        int r2 = srcrow[p + 2];
        int r3 = srcrow[p + 3];
        double c0 = dinvd[r0];
        double c1 = dinvd[r1];
        double c2 = dinvd[r2];
        double c3 = dinvd[r3];
        float2 h0 = *reinterpret_cast<const float2*>(h + (size_t)r0 * D + f);
        float2 h1 = *reinterpret_cast<const float2*>(h + (size_t)r1 * D + f);
        float2 h2 = *reinterpret_cast<const float2*>(h + (size_t)r2 * D + f);
        float2 h3 = *reinterpret_cast<const float2*>(h + (size_t)r3 * D + f);
        c0 *= dn; c1 *= dn; c2 *= dn; c3 *= dn;
        ax = fma((double)h0.x, c0, ax); ay = fma((double)h0.y, c0, ay);
        ax = fma((double)h1.x, c1, ax); ay = fma((double)h1.y, c1, ay);
        ax = fma((double)h2.x, c2, ax); ay = fma((double)h2.y, c2, ay);
        ax = fma((double)h3.x, c3, ax); ay = fma((double)h3.y, c3, ay);
    }
    for (; p < e; ++p) {
        int r = srcrow[p];
        double cf = dinvd[r] * dn;
        float2 hv = *reinterpret_cast<const float2*>(h + (size_t)r * D + f);
        ax = fma((double)hv.x, cf, ax);
        ay = fma((double)hv.y, cf, ay);
    }
    double dw = dn * dn;
    float2 hs = *reinterpret_cast<const float2*>(h + (size_t)node * D + f);
    ax = dleaky(ax + (double)hs.x * dw);
    ay = dleaky(ay + (double)hs.y * dw);
    *reinterpret_cast<float2*>(out + (size_t)node * D + f) =
        make_float2((float)ax, (float)ay);
}

// ---------------- fc2 (128->1): per-node scalar, f64 dot ----------------
__global__ __launch_bounds__(256) void fc2_d(const float* __restrict__ y,
                                             const float* __restrict__ w,
                                             double* __restrict__ s, int n) {
    int node = (int)((blockIdx.x * blockDim.x + threadIdx.x) >> 6);
    int lane = threadIdx.x & 63;
    if (node >= n) return;
    float2 yv = *reinterpret_cast<const float2*>(y + (size_t)node * D + lane * 2);
    float2 wv = *reinterpret_cast<const float2*>(w + lane * 2);
    double part = (double)yv.x * (double)wv.x + (double)yv.y * (double)wv.y;
#pragma unroll
    for (int off = 32; off > 0; off >>= 1) part += __shfl_down(part, off, 64);
    if (lane == 0) s[node] = dleaky(part);
}

// ---------------- pool: one block per graph, f64 tree reduce, no atomics ----------------
__global__ __launch_bounds__(256) void pool_d(const double* __restrict__ s,
                                              const int* __restrict__ batch,
                                              float* __restrict__ out, int n) {
    __shared__ double lsum[256];
    __shared__ int    lcnt[256];
    const int g = blockIdx.x;
    const int tid = threadIdx.x;
    double sum = 0.0; int cnt = 0;
    for (int i = tid; i < n; i += 256) {
        if (batch[i] == g) { sum += s[i]; cnt++; }
    }
    lsum[tid] = sum; lcnt[tid] = cnt;
    __syncthreads();
    for (int off = 128; off > 0; off >>= 1) {
        if (tid < off) { lsum[tid] += lsum[tid + off]; lcnt[tid] += lcnt[tid + off]; }
        __syncthreads();
    }
    if (tid == 0) out[g] = (float)(lsum[0] / (double)(lcnt[0] > 0 ? lcnt[0] : 1));
}

extern "C" void kernel_launch(void* const* d_in, const int* in_sizes, int n_in,
                              void* d_out, int out_size, void* d_ws, size_t ws_size,
                              hipStream_t stream) {
    const float* x    = (const float*)d_in[0];
    const int*   eidx = (const int*)d_in[1];
    const int*   batch= (const int*)d_in[2];
    const float* W0   = (const float*)d_in[3];
    const float* W1   = (const float*)d_in[4];
    const float* W2   = (const float*)d_in[5];
    const float* Wfc1 = (const float*)d_in[6];
    const float* Wfc2 = (const float*)d_in[7];
    float* out = (float*)d_out;

    const int* erow = eidx;
    const int* ecol = eidx + N_EDGES;

    char* ws = (char*)d_ws;
    int*    hist   = (int*)   (ws + 0);
    int*    start  = (int*)   (ws + 200064);
    int*    cursor = (int*)   (ws + 400384);
    int*    bsum   = (int*)   (ws + 600448);
    double* dinvd  = (double*)(ws + 600704);
    int*    srcrow = (int*)   (ws + 1000704);
    double* svec   = (double*)(ws + 4200704);
    float*  bufA   = (float*) (ws + 4600832);
    float*  bufB   = (float*) (ws + 30200832);

    zero_kernel<<<(N_NODES + 255) / 256, 256, 0, stream>>>(hist, N_NODES);
    hist_kernel<<<(N_EDGES + 255) / 256, 256, 0, stream>>>(ecol, hist, N_EDGES);
    dinv_kernel<<<(N_NODES + 255) / 256, 256, 0, stream>>>(hist, dinvd, N_NODES);

    const int NB = (N_NODES + 1023) / 1024;  // 49
    scan1<<<NB, 256, 0, stream>>>(hist, start, bsum, N_NODES);
    scan2<<<1, 256, 0, stream>>>(bsum, NB, start, N_NODES);
    scan3<<<NB, 256, 0, stream>>>(start, cursor, bsum, N_NODES);

    build_kernel<<<(N_EDGES + 255) / 256, 256, 0, stream>>>(erow, ecol, cursor, srcrow, N_EDGES);

    const int GEMM_GRID = (N_NODES + 63) / 64;   // 782
    const int AGG_GRID  = (N_NODES + 3) / 4;     // 12500

    gemm128_d<<<GEMM_GRID, 256, 0, stream>>>(x, W0, bufA, N_NODES, 0);
    agg_d<<<AGG_GRID, 256, 0, stream>>>(bufA, srcrow, start, dinvd, bufB, N_NODES);
    gemm128_d<<<GEMM_GRID, 256, 0, stream>>>(bufB, W1, bufA, N_NODES, 0);
    agg_d<<<AGG_GRID, 256, 0, stream>>>(bufA, srcrow, start, dinvd, bufB, N_NODES);
    gemm128_d<<<GEMM_GRID, 256, 0, stream>>>(bufB, W2, bufA, N_NODES, 0);
    agg_d<<<AGG_GRID, 256, 0, stream>>>(bufA, srcrow, start, dinvd, bufB, N_NODES);
    gemm128_d<<<GEMM_GRID, 256, 0, stream>>>(bufB, Wfc1, bufA, N_NODES, 1);

    fc2_d<<<AGG_GRID, 256, 0, stream>>>(bufA, Wfc2, svec, N_NODES);
    pool_d<<<NUM_GRAPHS, 256, 0, stream>>>(svec, batch, out, N_NODES);
}

// Round 5
// 581.479 us; speedup vs baseline: 1.6214x; 1.0447x over previous
//
#include <hip/hip_runtime.h>

#define N_NODES   50000
#define N_EDGES   800000
#define NUM_GRAPHS 64
#define D         128
#define SLOPE     0.01

__device__ __forceinline__ double dleaky(double v) { return v >= 0.0 ? v : SLOPE * v; }

// ---------------- zero ----------------
__global__ void zero_kernel(int* __restrict__ p, int n) {
    int i = blockIdx.x * blockDim.x + threadIdx.x;
    if (i < n) p[i] = 0;
}

// ---------------- degree histogram (by col) ----------------
__global__ void hist_kernel(const int* __restrict__ col, int* __restrict__ hist, int E) {
    int e = blockIdx.x * blockDim.x + threadIdx.x;
    if (e < E) atomicAdd(&hist[col[e]], 1);
}

// ---------------- dinv = 1/sqrt(deg+1) in double ----------------
__global__ void dinv_kernel(const int* __restrict__ hist, double* __restrict__ dinvd, int n) {
    int i = blockIdx.x * blockDim.x + threadIdx.x;
    if (i < n) dinvd[i] = 1.0 / sqrt((double)hist[i] + 1.0);
}

// ---------------- multi-block exclusive scan (3 kernels) ----------------
__global__ __launch_bounds__(256) void scan1(const int* __restrict__ hist,
                                             int* __restrict__ start,
                                             int* __restrict__ bsum, int n) {
    __shared__ int tmp[256];
    const int tid = threadIdx.x;
    int base = blockIdx.x * 1024 + tid * 4;
    int v[4]; int s = 0;
#pragma unroll
    for (int i = 0; i < 4; ++i) { int idx = base + i; v[i] = (idx < n) ? hist[idx] : 0; s += v[i]; }
    tmp[tid] = s;
    __syncthreads();
    for (int off = 1; off < 256; off <<= 1) {
        int t = (tid >= off) ? tmp[tid - off] : 0;
        __syncthreads();
        tmp[tid] += t;
        __syncthreads();
    }
    int run = tmp[tid] - s;
    if (tid == 255) bsum[blockIdx.x] = tmp[255];
#pragma unroll
    for (int i = 0; i < 4; ++i) { int idx = base + i; if (idx < n) start[idx] = run; run += v[i]; }
}

__global__ __launch_bounds__(256) void scan2(int* __restrict__ bsum, int nb,
                                             int* __restrict__ start, int n) {
    __shared__ int tmp[256];
    const int tid = threadIdx.x;
    int v = (tid < nb) ? bsum[tid] : 0;
    tmp[tid] = v;
    __syncthreads();
    for (int off = 1; off < 256; off <<= 1) {
        int t = (tid >= off) ? tmp[tid - off] : 0;
        __syncthreads();
        tmp[tid] += t;
        __syncthreads();
    }
    if (tid < nb) bsum[tid] = tmp[tid] - v;
    if (tid == 255) start[n] = tmp[255];
}

__global__ __launch_bounds__(256) void scan3(int* __restrict__ start, int* __restrict__ cursor,
                                             const int* __restrict__ bsum, int n) {
    int off = bsum[blockIdx.x];
    int base = blockIdx.x * 1024 + threadIdx.x * 4;
#pragma unroll
    for (int i = 0; i < 4; ++i) {
        int j = base + i;
        if (j < n) { int v = start[j] + off; start[j] = v; cursor[j] = v; }
    }
}

// ---------------- CSR build: scatter source rows, sorted by col ----------------
__global__ void build_kernel(const int* __restrict__ row, const int* __restrict__ col,
                             int* __restrict__ cursor, int* __restrict__ srcrow, int E) {
    int e = blockIdx.x * blockDim.x + threadIdx.x;
    if (e >= E) return;
    int p = atomicAdd(&cursor[col[e]], 1);
    srcrow[p] = row[e];
}

// ---------------- graph boundaries from sorted batch: gstart[65] ----------------
__global__ void gbound_kernel(const int* __restrict__ batch, int* __restrict__ gstart, int n) {
    int i = blockIdx.x * blockDim.x + threadIdx.x;
    if (i >= n) return;
    int b = batch[i];
    int prev = (i == 0) ? -1 : batch[i - 1];
    for (int g = prev + 1; g <= b; ++g) gstart[g] = i;
    if (i == n - 1) {
        for (int g = b + 1; g <= NUM_GRAPHS; ++g) gstart[g] = n;
    }
}

// ---------------- GEMM: C[M x 128] = A[M x 128] @ W[128 x 128], f64 accumulate ----------------
// Thread (rg,cg) computes rows rg*4..+3, cols {cg + 16j}. Ws reads are scalar b64 at
// 8B lane stride -> conflict-free; As rows land on distinct bank quads (pad 33).
__global__ __launch_bounds__(256) void gemm128_d(const float* __restrict__ A,
                                                 const float* __restrict__ W,
                                                 float* __restrict__ C, int M, int act) {
    __shared__ double As[64][33];
    __shared__ double Ws[32][129];
    const int tid = threadIdx.x;
    const int rg = tid >> 4;
    const int cg = tid & 15;
    const int rowBase = blockIdx.x * 64;

    double acc[4][8];
#pragma unroll
    for (int r = 0; r < 4; ++r)
#pragma unroll
        for (int j = 0; j < 8; ++j) acc[r][j] = 0.0;

    const int lr = tid >> 2;
    const int lc = (tid & 3) * 8;
    const int wr = tid >> 3;
    const int wc = (tid & 7) * 16;

    for (int kc = 0; kc < 128; kc += 32) {
        {
            int grow = rowBase + lr;
            float4 a0 = make_float4(0.f, 0.f, 0.f, 0.f), a1 = a0;
            if (grow < M) {
                const float4* src = reinterpret_cast<const float4*>(A + (size_t)grow * D + kc + lc);
                a0 = src[0]; a1 = src[1];
            }
            *reinterpret_cast<double2*>(&As[lr][lc + 0]) = make_double2((double)a0.x, (double)a0.y);
            *reinterpret_cast<double2*>(&As[lr][lc + 2]) = make_double2((double)a0.z, (double)a0.w);
            *reinterpret_cast<double2*>(&As[lr][lc + 4]) = make_double2((double)a1.x, (double)a1.y);
            *reinterpret_cast<double2*>(&As[lr][lc + 6]) = make_double2((double)a1.z, (double)a1.w);
        }
        {
            const float4* src = reinterpret_cast<const float4*>(W + (size_t)(kc + wr) * D + wc);
#pragma unroll
            for (int i = 0; i < 4; ++i) {
                float4 wv = src[i];
                *reinterpret_cast<double2*>(&Ws[wr][wc + 4 * i + 0]) = make_double2((double)wv.x, (double)wv.y);
                *reinterpret_cast<double2*>(&Ws[wr][wc + 4 * i + 2]) = make_double2((double)wv.z, (double)wv.w);
            }
        }
        __syncthreads();
#pragma unroll
        for (int k = 0; k < 32; ++k) {
            double xv0 = As[rg * 4 + 0][k];
            double xv1 = As[rg * 4 + 1][k];
            double xv2 = As[rg * 4 + 2][k];
            double xv3 = As[rg * 4 + 3][k];
            double w0 = Ws[k][cg +   0];
            double w1 = Ws[k][cg +  16];
            double w2 = Ws[k][cg +  32];
            double w3 = Ws[k][cg +  48];
            double w4 = Ws[k][cg +  64];
            double w5 = Ws[k][cg +  80];
            double w6 = Ws[k][cg +  96];
            double w7 = Ws[k][cg + 112];
            acc[0][0] = fma(xv0, w0, acc[0][0]); acc[0][1] = fma(xv0, w1, acc[0][1]);
            acc[0][2] = fma(xv0, w2, acc[0][2]); acc[0][3] = fma(xv0, w3, acc[0][3]);
            acc[0][4] = fma(xv0, w4, acc[0][4]); acc[0][5] = fma(xv0, w5, acc[0][5]);
            acc[0][6] = fma(xv0, w6, acc[0][6]); acc[0][7] = fma(xv0, w7, acc[0][7]);
            acc[1][0] = fma(xv1, w0, acc[1][0]); acc[1][1] = fma(xv1, w1, acc[1][1]);
            acc[1][2] = fma(xv1, w2, acc[1][2]); acc[1][3] = fma(xv1, w3, acc[1][3]);
            acc[1][4] = fma(xv1, w4, acc[1][4]); acc[1][5] = fma(xv1, w5, acc[1][5]);
            acc[1][6] = fma(xv1, w6, acc[1][6]); acc[1][7] = fma(xv1, w7, acc[1][7]);
            acc[2][0] = fma(xv2, w0, acc[2][0]); acc[2][1] = fma(xv2, w1, acc[2][1]);
            acc[2][2] = fma(xv2, w2, acc[2][2]); acc[2][3] = fma(xv2, w3, acc[2][3]);
            acc[2][4] = fma(xv2, w4, acc[2][4]); acc[2][5] = fma(xv2, w5, acc[2][5]);
            acc[2][6] = fma(xv2, w6, acc[2][6]); acc[2][7] = fma(xv2, w7, acc[2][7]);
            acc[3][0] = fma(xv3, w0, acc[3][0]); acc[3][1] = fma(xv3, w1, acc[3][1]);
            acc[3][2] = fma(xv3, w2, acc[3][2]); acc[3][3] = fma(xv3, w3, acc[3][3]);
            acc[3][4] = fma(xv3, w4, acc[3][4]); acc[3][5] = fma(xv3, w5, acc[3][5]);
            acc[3][6] = fma(xv3, w6, acc[3][6]); acc[3][7] = fma(xv3, w7, acc[3][7]);
        }
        __syncthreads();
    }

#pragma unroll
    for (int r = 0; r < 4; ++r) {
        int grow = rowBase + rg * 4 + r;
        if (grow < M) {
#pragma unroll
            for (int j = 0; j < 8; ++j) {
                double v = act ? dleaky(acc[r][j]) : acc[r][j];
                C[(size_t)grow * D + cg + 16 * j] = (float)v;
            }
        }
    }
}

// ---------------- aggregation + self-loop + leaky, f64 accumulate ----------------
__global__ __launch_bounds__(256) void agg_d(const float* __restrict__ h,
                                             const int* __restrict__ srcrow,
                                             const int* __restrict__ start,
                                             const double* __restrict__ dinvd,
                                             float* __restrict__ out, int n) {
    int node = (int)((blockIdx.x * blockDim.x + threadIdx.x) >> 6);
    int lane = threadIdx.x & 63;
    if (node >= n) return;
    int s = start[node], e = start[node + 1];
    double dn = dinvd[node];
    const int f = lane * 2;
    double ax = 0.0, ay = 0.0;
    int p = s;
    for (; p + 8 <= e; p += 8) {
        int r[8]; double c[8]; float2 hv[8];
#pragma unroll
        for (int i = 0; i < 8; ++i) r[i] = srcrow[p + i];
#pragma unroll
        for (int i = 0; i < 8; ++i) c[i] = dinvd[r[i]];
#pragma unroll
        for (int i = 0; i < 8; ++i)
            hv[i] = *reinterpret_cast<const float2*>(h + (size_t)r[i] * D + f);
#pragma unroll
        for (int i = 0; i < 8; ++i) {
            double cf = c[i] * dn;
            ax = fma((double)hv[i].x, cf, ax);
            ay = fma((double)hv[i].y, cf, ay);
        }
    }
    for (; p + 4 <= e; p += 4) {
        int r0 = srcrow[p + 0], r1 = srcrow[p + 1], r2 = srcrow[p + 2], r3 = srcrow[p + 3];
        double c0 = dinvd[r0], c1 = dinvd[r1], c2 = dinvd[r2], c3 = dinvd[r3];
        float2 h0 = *reinterpret_cast<const float2*>(h + (size_t)r0 * D + f);
        float2 h1 = *reinterpret_cast<const float2*>(h + (size_t)r1 * D + f);
        float2 h2 = *reinterpret_cast<const float2*>(h + (size_t)r2 * D + f);
        float2 h3 = *reinterpret_cast<const float2*>(h + (size_t)r3 * D + f);
        c0 *= dn; c1 *= dn; c2 *= dn; c3 *= dn;
        ax = fma((double)h0.x, c0, ax); ay = fma((double)h0.y, c0, ay);
        ax = fma((double)h1.x, c1, ax); ay = fma((double)h1.y, c1, ay);
        ax = fma((double)h2.x, c2, ax); ay = fma((double)h2.y, c2, ay);
        ax = fma((double)h3.x, c3, ax); ay = fma((double)h3.y, c3, ay);
    }
    for (; p < e; ++p) {
        int r = srcrow[p];
        double cf = dinvd[r] * dn;
        float2 hv = *reinterpret_cast<const float2*>(h + (size_t)r * D + f);
        ax = fma((double)hv.x, cf, ax);
        ay = fma((double)hv.y, cf, ay);
    }
    double dw = dn * dn;
    float2 hs = *reinterpret_cast<const float2*>(h + (size_t)node * D + f);
    ax = dleaky(ax + (double)hs.x * dw);
    ay = dleaky(ay + (double)hs.y * dw);
    *reinterpret_cast<float2*>(out + (size_t)node * D + f) =
        make_float2((float)ax, (float)ay);
}

// ---------------- fc2 (128->1): per-node scalar, f64 dot ----------------
__global__ __launch_bounds__(256) void fc2_d(const float* __restrict__ y,
                                             const float* __restrict__ w,
                                             double* __restrict__ s, int n) {
    int node = (int)((blockIdx.x * blockDim.x + threadIdx.x) >> 6);
    int lane = threadIdx.x & 63;
    if (node >= n) return;
    float2 yv = *reinterpret_cast<const float2*>(y + (size_t)node * D + lane * 2);
    float2 wv = *reinterpret_cast<const float2*>(w + lane * 2);
    double part = (double)yv.x * (double)wv.x + (double)yv.y * (double)wv.y;
#pragma unroll
    for (int off = 32; off > 0; off >>= 1) part += __shfl_down(part, off, 64);
    if (lane == 0) s[node] = dleaky(part);
}

// ---------------- pool: block per graph over its contiguous node range ----------------
__global__ __launch_bounds__(256) void pool2(const double* __restrict__ s,
                                             const int* __restrict__ gstart,
                                             float* __restrict__ out) {
    __shared__ double lsum[256];
    const int g = blockIdx.x;
    const int tid = threadIdx.x;
    const int s0 = gstart[g], s1 = gstart[g + 1];
    double sum = 0.0;
    for (int i = s0 + tid; i < s1; i += 256) sum += s[i];
    lsum[tid] = sum;
    __syncthreads();
    for (int off = 128; off > 0; off >>= 1) {
        if (tid < off) lsum[tid] += lsum[tid + off];
        __syncthreads();
    }
    if (tid == 0) {
        int cnt = s1 - s0;
        out[g] = (float)(lsum[0] / (double)(cnt > 0 ? cnt : 1));
    }
}

extern "C" void kernel_launch(void* const* d_in, const int* in_sizes, int n_in,
                              void* d_out, int out_size, void* d_ws, size_t ws_size,
                              hipStream_t stream) {
    const float* x    = (const float*)d_in[0];
    const int*   eidx = (const int*)d_in[1];
    const int*   batch= (const int*)d_in[2];
    const float* W0   = (const float*)d_in[3];
    const float* W1   = (const float*)d_in[4];
    const float* W2   = (const float*)d_in[5];
    const float* Wfc1 = (const float*)d_in[6];
    const float* Wfc2 = (const float*)d_in[7];
    float* out = (float*)d_out;

    const int* erow = eidx;
    const int* ecol = eidx + N_EDGES;

    char* ws = (char*)d_ws;
    int*    hist   = (int*)   (ws + 0);
    int*    start  = (int*)   (ws + 200064);
    int*    cursor = (int*)   (ws + 400384);   // dead after build -> reused as gstart
    int*    bsum   = (int*)   (ws + 600448);
    double* dinvd  = (double*)(ws + 600704);
    int*    srcrow = (int*)   (ws + 1000704);
    double* svec   = (double*)(ws + 4200704);
    float*  bufA   = (float*) (ws + 4600832);
    float*  bufB   = (float*) (ws + 30200832);
    int*    gstart = cursor;

    zero_kernel<<<(N_NODES + 255) / 256, 256, 0, stream>>>(hist, N_NODES);
    hist_kernel<<<(N_EDGES + 255) / 256, 256, 0, stream>>>(ecol, hist, N_EDGES);
    dinv_kernel<<<(N_NODES + 255) / 256, 256, 0, stream>>>(hist, dinvd, N_NODES);

    const int NB = (N_NODES + 1023) / 1024;  // 49
    scan1<<<NB, 256, 0, stream>>>(hist, start, bsum, N_NODES);
    scan2<<<1, 256, 0, stream>>>(bsum, NB, start, N_NODES);
    scan3<<<NB, 256, 0, stream>>>(start, cursor, bsum, N_NODES);

    build_kernel<<<(N_EDGES + 255) / 256, 256, 0, stream>>>(erow, ecol, cursor, srcrow, N_EDGES);
    gbound_kernel<<<(N_NODES + 255) / 256, 256, 0, stream>>>(batch, gstart, N_NODES);

    const int GEMM_GRID = (N_NODES + 63) / 64;   // 782
    const int AGG_GRID  = (N_NODES + 3) / 4;     // 12500

    gemm128_d<<<GEMM_GRID, 256, 0, stream>>>(x, W0, bufA, N_NODES, 0);
    agg_d<<<AGG_GRID, 256, 0, stream>>>(bufA, srcrow, start, dinvd, bufB, N_NODES);
    gemm128_d<<<GEMM_GRID, 256, 0, stream>>>(bufB, W1, bufA, N_NODES, 0);
    agg_d<<<AGG_GRID, 256, 0, stream>>>(bufA, srcrow, start, dinvd, bufB, N_NODES);
    gemm128_d<<<GEMM_GRID, 256, 0, stream>>>(bufB, W2, bufA, N_NODES, 0);
    agg_d<<<AGG_GRID, 256, 0, stream>>>(bufA, srcrow, start, dinvd, bufB, N_NODES);
    gemm128_d<<<GEMM_GRID, 256, 0, stream>>>(bufB, Wfc1, bufA, N_NODES, 1);

    fc2_d<<<AGG_GRID, 256, 0, stream>>>(bufA, Wfc2, svec, N_NODES);
    pool2<<<NUM_GRAPHS, 256, 0, stream>>>(svec, gstart, out);
}

// Round 6
// 509.761 us; speedup vs baseline: 1.8495x; 1.1407x over previous
//
#include <hip/hip_runtime.h>

#define N_NODES   50000
#define N_EDGES   800000
#define NUM_GRAPHS 64
#define D         128
#define SLOPE     0.01

__device__ __forceinline__ double dleaky(double v) { return v >= 0.0 ? v : SLOPE * v; }

// ---------------- zero ----------------
__global__ void zero_kernel(int* __restrict__ p, int n) {
    int i = blockIdx.x * blockDim.x + threadIdx.x;
    if (i < n) p[i] = 0;
}

// ---------------- degree histogram (by col) ----------------
__global__ void hist_kernel(const int* __restrict__ col, int* __restrict__ hist, int E) {
    int e = blockIdx.x * blockDim.x + threadIdx.x;
    if (e < E) atomicAdd(&hist[col[e]], 1);
}

// ---------------- dinv = 1/sqrt(deg+1) in double ----------------
__global__ void dinv_kernel(const int* __restrict__ hist, double* __restrict__ dinvd, int n) {
    int i = blockIdx.x * blockDim.x + threadIdx.x;
    if (i < n) dinvd[i] = 1.0 / sqrt((double)hist[i] + 1.0);
}

// ---------------- multi-block exclusive scan (3 kernels) ----------------
__global__ __launch_bounds__(256) void scan1(const int* __restrict__ hist,
                                             int* __restrict__ start,
                                             int* __restrict__ bsum, int n) {
    __shared__ int tmp[256];
    const int tid = threadIdx.x;
    int base = blockIdx.x * 1024 + tid * 4;
    int v[4]; int s = 0;
#pragma unroll
    for (int i = 0; i < 4; ++i) { int idx = base + i; v[i] = (idx < n) ? hist[idx] : 0; s += v[i]; }
    tmp[tid] = s;
    __syncthreads();
    for (int off = 1; off < 256; off <<= 1) {
        int t = (tid >= off) ? tmp[tid - off] : 0;
        __syncthreads();
        tmp[tid] += t;
        __syncthreads();
    }
    int run = tmp[tid] - s;
    if (tid == 255) bsum[blockIdx.x] = tmp[255];
#pragma unroll
    for (int i = 0; i < 4; ++i) { int idx = base + i; if (idx < n) start[idx] = run; run += v[i]; }
}

__global__ __launch_bounds__(256) void scan2(int* __restrict__ bsum, int nb,
                                             int* __restrict__ start, int n) {
    __shared__ int tmp[256];
    const int tid = threadIdx.x;
    int v = (tid < nb) ? bsum[tid] : 0;
    tmp[tid] = v;
    __syncthreads();
    for (int off = 1; off < 256; off <<= 1) {
        int t = (tid >= off) ? tmp[tid - off] : 0;
        __syncthreads();
        tmp[tid] += t;
        __syncthreads();
    }
    if (tid < nb) bsum[tid] = tmp[tid] - v;
    if (tid == 255) start[n] = tmp[255];
}

__global__ __launch_bounds__(256) void scan3(int* __restrict__ start, int* __restrict__ cursor,
                                             const int* __restrict__ bsum, int n) {
    int off = bsum[blockIdx.x];
    int base = blockIdx.x * 1024 + threadIdx.x * 4;
#pragma unroll
    for (int i = 0; i < 4; ++i) {
        int j = base + i;
        if (j < n) { int v = start[j] + off; start[j] = v; cursor[j] = v; }
    }
}

// ---------------- CSR build: scatter source rows, sorted by col ----------------
__global__ void build_kernel(const int* __restrict__ row, const int* __restrict__ col,
                             int* __restrict__ cursor, int* __restrict__ srcrow, int E) {
    int e = blockIdx.x * blockDim.x + threadIdx.x;
    if (e >= E) return;
    int p = atomicAdd(&cursor[col[e]], 1);
    srcrow[p] = row[e];
}

// ---------------- graph boundaries from sorted batch: gstart[65] ----------------
__global__ void gbound_kernel(const int* __restrict__ batch, int* __restrict__ gstart, int n) {
    int i = blockIdx.x * blockDim.x + threadIdx.x;
    if (i >= n) return;
    int b = batch[i];
    int prev = (i == 0) ? -1 : batch[i - 1];
    for (int g = prev + 1; g <= b; ++g) gstart[g] = i;
    if (i == n - 1) {
        for (int g = b + 1; g <= NUM_GRAPHS; ++g) gstart[g] = n;
    }
}

// ---------------- GEMM: C[M x 128] = A[M x 128] @ W[128 x 128], f64 accumulate ----------------
// As staged f64 (16.9 KB), Ws staged f32 (16.5 KB, exact-converted to f64 at read):
// 33.4 KB LDS -> 4 blocks/CU. A-chunk prefetched into regs during compute.
// Thread (rg,cg): rows rg*4..+3, cols {cg+16j}. All LDS reads conflict-free
// (As: 4-row broadcast on distinct bank quads; Ws: 16 consecutive banks x4 broadcast).
__global__ __launch_bounds__(256, 4) void gemm128_d(const float* __restrict__ A,
                                                    const float* __restrict__ W,
                                                    float* __restrict__ C, int M, int act) {
    __shared__ double As[64][33];
    __shared__ float  Ws[32][129];
    const int tid = threadIdx.x;
    const int rg = tid >> 4;
    const int cg = tid & 15;
    const int rowBase = blockIdx.x * 64;

    double acc[4][8];
#pragma unroll
    for (int r = 0; r < 4; ++r)
#pragma unroll
        for (int j = 0; j < 8; ++j) acc[r][j] = 0.0;

    const int lr = tid >> 2;            // 0..63  A stage row
    const int lc = (tid & 3) * 8;       // 0,8,16,24
    const int wr = tid & 31;            // 0..31  W stage row (within chunk)
    const int wc = (tid >> 5) * 16;     // 0..112

    const int growA = rowBase + lr;
    const bool haveA = (growA < M);

    // prefetch A chunk 0
    float4 a0 = make_float4(0.f, 0.f, 0.f, 0.f), a1 = a0;
    if (haveA) {
        const float4* src = reinterpret_cast<const float4*>(A + (size_t)growA * D + 0 + lc);
        a0 = src[0]; a1 = src[1];
    }

    for (int kc = 0; kc < 128; kc += 32) {
        // write As (f64) from prefetched regs
        *reinterpret_cast<double2*>(&As[lr][lc + 0]) = make_double2((double)a0.x, (double)a0.y);
        *reinterpret_cast<double2*>(&As[lr][lc + 2]) = make_double2((double)a0.z, (double)a0.w);
        *reinterpret_cast<double2*>(&As[lr][lc + 4]) = make_double2((double)a1.x, (double)a1.y);
        *reinterpret_cast<double2*>(&As[lr][lc + 6]) = make_double2((double)a1.z, (double)a1.w);
        // load + write Ws (f32) for this chunk (W is L2-hot: 64 KB shared by all blocks)
        {
            const float4* src = reinterpret_cast<const float4*>(W + (size_t)(kc + wr) * D + wc);
#pragma unroll
            for (int i = 0; i < 4; ++i)
                *reinterpret_cast<float4*>(&Ws[wr][wc + 4 * i]) = src[i];
        }
        __syncthreads();

        // issue next A-chunk loads; latency hides under compute
        if (kc + 32 < 128 && haveA) {
            const float4* src = reinterpret_cast<const float4*>(A + (size_t)growA * D + (kc + 32) + lc);
            a0 = src[0]; a1 = src[1];
        }

#pragma unroll
        for (int k = 0; k < 32; ++k) {
            double xv0 = As[rg * 4 + 0][k];
            double xv1 = As[rg * 4 + 1][k];
            double xv2 = As[rg * 4 + 2][k];
            double xv3 = As[rg * 4 + 3][k];
            double w0 = (double)Ws[k][cg +   0];
            double w1 = (double)Ws[k][cg +  16];
            double w2 = (double)Ws[k][cg +  32];
            double w3 = (double)Ws[k][cg +  48];
            double w4 = (double)Ws[k][cg +  64];
            double w5 = (double)Ws[k][cg +  80];
            double w6 = (double)Ws[k][cg +  96];
            double w7 = (double)Ws[k][cg + 112];
            acc[0][0] = fma(xv0, w0, acc[0][0]); acc[0][1] = fma(xv0, w1, acc[0][1]);
            acc[0][2] = fma(xv0, w2, acc[0][2]); acc[0][3] = fma(xv0, w3, acc[0][3]);
            acc[0][4] = fma(xv0, w4, acc[0][4]); acc[0][5] = fma(xv0, w5, acc[0][5]);
            acc[0][6] = fma(xv0, w6, acc[0][6]); acc[0][7] = fma(xv0, w7, acc[0][7]);
            acc[1][0] = fma(xv1, w0, acc[1][0]); acc[1][1] = fma(xv1, w1, acc[1][1]);
            acc[1][2] = fma(xv1, w2, acc[1][2]); acc[1][3] = fma(xv1, w3, acc[1][3]);
            acc[1][4] = fma(xv1, w4, acc[1][4]); acc[1][5] = fma(xv1, w5, acc[1][5]);
            acc[1][6] = fma(xv1, w6, acc[1][6]); acc[1][7] = fma(xv1, w7, acc[1][7]);
            acc[2][0] = fma(xv2, w0, acc[2][0]); acc[2][1] = fma(xv2, w1, acc[2][1]);
            acc[2][2] = fma(xv2, w2, acc[2][2]); acc[2][3] = fma(xv2, w3, acc[2][3]);
            acc[2][4] = fma(xv2, w4, acc[2][4]); acc[2][5] = fma(xv2, w5, acc[2][5]);
            acc[2][6] = fma(xv2, w6, acc[2][6]); acc[2][7] = fma(xv2, w7, acc[2][7]);
            acc[3][0] = fma(xv3, w0, acc[3][0]); acc[3][1] = fma(xv3, w1, acc[3][1]);
            acc[3][2] = fma(xv3, w2, acc[3][2]); acc[3][3] = fma(xv3, w3, acc[3][3]);
            acc[3][4] = fma(xv3, w4, acc[3][4]); acc[3][5] = fma(xv3, w5, acc[3][5]);
            acc[3][6] = fma(xv3, w6, acc[3][6]); acc[3][7] = fma(xv3, w7, acc[3][7]);
        }
        __syncthreads();
    }

#pragma unroll
    for (int r = 0; r < 4; ++r) {
        int grow = rowBase + rg * 4 + r;
        if (grow < M) {
#pragma unroll
            for (int j = 0; j < 8; ++j) {
                double v = act ? dleaky(acc[r][j]) : acc[r][j];
                C[(size_t)grow * D + cg + 16 * j] = (float)v;
            }
        }
    }
}

// ---------------- aggregation + self-loop + leaky, f64 accumulate ----------------
__global__ __launch_bounds__(256) void agg_d(const float* __restrict__ h,
                                             const int* __restrict__ srcrow,
                                             const int* __restrict__ start,
                                             const double* __restrict__ dinvd,
                                             float* __restrict__ out, int n) {
    int node = (int)((blockIdx.x * blockDim.x + threadIdx.x) >> 6);
    int lane = threadIdx.x & 63;
    if (node >= n) return;
    int s = start[node], e = start[node + 1];
    double dn = dinvd[node];
    const int f = lane * 2;
    double ax = 0.0, ay = 0.0;
    int p = s;
    for (; p + 8 <= e; p += 8) {
        int r[8]; double c[8]; float2 hv[8];
#pragma unroll
        for (int i = 0; i < 8; ++i) r[i] = srcrow[p + i];
#pragma unroll
        for (int i = 0; i < 8; ++i) c[i] = dinvd[r[i]];
#pragma unroll
        for (int i = 0; i < 8; ++i)
            hv[i] = *reinterpret_cast<const float2*>(h + (size_t)r[i] * D + f);
#pragma unroll
        for (int i = 0; i < 8; ++i) {
            double cf = c[i] * dn;
            ax = fma((double)hv[i].x, cf, ax);
            ay = fma((double)hv[i].y, cf, ay);
        }
    }
    for (; p + 4 <= e; p += 4) {
        int r0 = srcrow[p + 0], r1 = srcrow[p + 1], r2 = srcrow[p + 2], r3 = srcrow[p + 3];
        double c0 = dinvd[r0], c1 = dinvd[r1], c2 = dinvd[r2], c3 = dinvd[r3];
        float2 h0 = *reinterpret_cast<const float2*>(h + (size_t)r0 * D + f);
        float2 h1 = *reinterpret_cast<const float2*>(h + (size_t)r1 * D + f);
        float2 h2 = *reinterpret_cast<const float2*>(h + (size_t)r2 * D + f);
        float2 h3 = *reinterpret_cast<const float2*>(h + (size_t)r3 * D + f);
        c0 *= dn; c1 *= dn; c2 *= dn; c3 *= dn;
        ax = fma((double)h0.x, c0, ax); ay = fma((double)h0.y, c0, ay);
        ax = fma((double)h1.x, c1, ax); ay = fma((double)h1.y, c1, ay);
        ax = fma((double)h2.x, c2, ax); ay = fma((double)h2.y, c2, ay);
        ax = fma((double)h3.x, c3, ax); ay = fma((double)h3.y, c3, ay);
    }
    for (; p < e; ++p) {
        int r = srcrow[p];
        double cf = dinvd[r] * dn;
        float2 hv = *reinterpret_cast<const float2*>(h + (size_t)r * D + f);
        ax = fma((double)hv.x, cf, ax);
        ay = fma((double)hv.y, cf, ay);
    }
    double dw = dn * dn;
    float2 hs = *reinterpret_cast<const float2*>(h + (size_t)node * D + f);
    ax = dleaky(ax + (double)hs.x * dw);
    ay = dleaky(ay + (double)hs.y * dw);
    *reinterpret_cast<float2*>(out + (size_t)node * D + f) =
        make_float2((float)ax, (float)ay);
}

// ---------------- fc2 (128->1): per-node scalar, f64 dot ----------------
__global__ __launch_bounds__(256) void fc2_d(const float* __restrict__ y,
                                             const float* __restrict__ w,
                                             double* __restrict__ s, int n) {
    int node = (int)((blockIdx.x * blockDim.x + threadIdx.x) >> 6);
    int lane = threadIdx.x & 63;
    if (node >= n) return;
    float2 yv = *reinterpret_cast<const float2*>(y + (size_t)node * D + lane * 2);
    float2 wv = *reinterpret_cast<const float2*>(w + lane * 2);
    double part = (double)yv.x * (double)wv.x + (double)yv.y * (double)wv.y;
#pragma unroll
    for (int off = 32; off > 0; off >>= 1) part += __shfl_down(part, off, 64);
    if (lane == 0) s[node] = dleaky(part);
}

// ---------------- pool: block per graph over its contiguous node range ----------------
__global__ __launch_bounds__(256) void pool2(const double* __restrict__ s,
                                             const int* __restrict__ gstart,
                                             float* __restrict__ out) {
    __shared__ double lsum[256];
    const int g = blockIdx.x;
    const int tid = threadIdx.x;
    const int s0 = gstart[g], s1 = gstart[g + 1];
    double sum = 0.0;
    for (int i = s0 + tid; i < s1; i += 256) sum += s[i];
    lsum[tid] = sum;
    __syncthreads();
    for (int off = 128; off > 0; off >>= 1) {
        if (tid < off) lsum[tid] += lsum[tid + off];
        __syncthreads();
    }
    if (tid == 0) {
        int cnt = s1 - s0;
        out[g] = (float)(lsum[0] / (double)(cnt > 0 ? cnt : 1));
    }
}

extern "C" void kernel_launch(void* const* d_in, const int* in_sizes, int n_in,
                              void* d_out, int out_size, void* d_ws, size_t ws_size,
                              hipStream_t stream) {
    const float* x    = (const float*)d_in[0];
    const int*   eidx = (const int*)d_in[1];
    const int*   batch= (const int*)d_in[2];
    const float* W0   = (const float*)d_in[3];
    const float* W1   = (const float*)d_in[4];
    const float* W2   = (const float*)d_in[5];
    const float* Wfc1 = (const float*)d_in[6];
    const float* Wfc2 = (const float*)d_in[7];
    float* out = (float*)d_out;

    const int* erow = eidx;
    const int* ecol = eidx + N_EDGES;

    char* ws = (char*)d_ws;
    int*    hist   = (int*)   (ws + 0);
    int*    start  = (int*)   (ws + 200064);
    int*    cursor = (int*)   (ws + 400384);   // dead after build -> reused as gstart
    int*    bsum   = (int*)   (ws + 600448);
    double* dinvd  = (double*)(ws + 600704);
    int*    srcrow = (int*)   (ws + 1000704);
    double* svec   = (double*)(ws + 4200704);
    float*  bufA   = (float*) (ws + 4600832);
    float*  bufB   = (float*) (ws + 30200832);
    int*    gstart = cursor;

    zero_kernel<<<(N_NODES + 255) / 256, 256, 0, stream>>>(hist, N_NODES);
    hist_kernel<<<(N_EDGES + 255) / 256, 256, 0, stream>>>(ecol, hist, N_EDGES);
    dinv_kernel<<<(N_NODES + 255) / 256, 256, 0, stream>>>(hist, dinvd, N_NODES);

    const int NB = (N_NODES + 1023) / 1024;  // 49
    scan1<<<NB, 256, 0, stream>>>(hist, start, bsum, N_NODES);
    scan2<<<1, 256, 0, stream>>>(bsum, NB, start, N_NODES);
    scan3<<<NB, 256, 0, stream>>>(start, cursor, bsum, N_NODES);

    build_kernel<<<(N_EDGES + 255) / 256, 256, 0, stream>>>(erow, ecol, cursor, srcrow, N_EDGES);
    gbound_kernel<<<(N_NODES + 255) / 256, 256, 0, stream>>>(batch, gstart, N_NODES);

    const int GEMM_GRID = (N_NODES + 63) / 64;   // 782
    const int AGG_GRID  = (N_NODES + 3) / 4;     // 12500

    gemm128_d<<<GEMM_GRID, 256, 0, stream>>>(x, W0, bufA, N_NODES, 0);
    agg_d<<<AGG_GRID, 256, 0, stream>>>(bufA, srcrow, start, dinvd, bufB, N_NODES);
    gemm128_d<<<GEMM_GRID, 256, 0, stream>>>(bufB, W1, bufA, N_NODES, 0);
    agg_d<<<AGG_GRID, 256, 0, stream>>>(bufA, srcrow, start, dinvd, bufB, N_NODES);
    gemm128_d<<<GEMM_GRID, 256, 0, stream>>>(bufB, W2, bufA, N_NODES, 0);
    agg_d<<<AGG_GRID, 256, 0, stream>>>(bufA, srcrow, start, dinvd, bufB, N_NODES);
    gemm128_d<<<GEMM_GRID, 256, 0, stream>>>(bufB, Wfc1, bufA, N_NODES, 1);

    fc2_d<<<AGG_GRID, 256, 0, stream>>>(bufA, Wfc2, svec, N_NODES);
    pool2<<<NUM_GRAPHS, 256, 0, stream>>>(svec, gstart, out);
}

// Round 7
// 500.269 us; speedup vs baseline: 1.8846x; 1.0190x over previous
//
#include <hip/hip_runtime.h>

#define N_NODES   50000
#define N_EDGES   800000
#define NUM_GRAPHS 64
#define D         128
#define SLOPE     0.01

__device__ __forceinline__ double dleaky(double v) { return v >= 0.0 ? v : SLOPE * v; }

// ---------------- zero ----------------
__global__ void zero_kernel(int* __restrict__ p, int n) {
    int i = blockIdx.x * blockDim.x + threadIdx.x;
    if (i < n) p[i] = 0;
}

// ---------------- degree histogram (by col) ----------------
__global__ void hist_kernel(const int* __restrict__ col, int* __restrict__ hist, int E) {
    int e = blockIdx.x * blockDim.x + threadIdx.x;
    if (e < E) atomicAdd(&hist[col[e]], 1);
}

// ---------------- dinv = 1/sqrt(deg+1) in double ----------------
__global__ void dinv_kernel(const int* __restrict__ hist, double* __restrict__ dinvd, int n) {
    int i = blockIdx.x * blockDim.x + threadIdx.x;
    if (i < n) dinvd[i] = 1.0 / sqrt((double)hist[i] + 1.0);
}

// ---------------- multi-block exclusive scan (3 kernels) ----------------
__global__ __launch_bounds__(256) void scan1(const int* __restrict__ hist,
                                             int* __restrict__ start,
                                             int* __restrict__ bsum, int n) {
    __shared__ int tmp[256];
    const int tid = threadIdx.x;
    int base = blockIdx.x * 1024 + tid * 4;
    int v[4]; int s = 0;
#pragma unroll
    for (int i = 0; i < 4; ++i) { int idx = base + i; v[i] = (idx < n) ? hist[idx] : 0; s += v[i]; }
    tmp[tid] = s;
    __syncthreads();
    for (int off = 1; off < 256; off <<= 1) {
        int t = (tid >= off) ? tmp[tid - off] : 0;
        __syncthreads();
        tmp[tid] += t;
        __syncthreads();
    }
    int run = tmp[tid] - s;
    if (tid == 255) bsum[blockIdx.x] = tmp[255];
#pragma unroll
    for (int i = 0; i < 4; ++i) { int idx = base + i; if (idx < n) start[idx] = run; run += v[i]; }
}

__global__ __launch_bounds__(256) void scan2(int* __restrict__ bsum, int nb,
                                             int* __restrict__ start, int n) {
    __shared__ int tmp[256];
    const int tid = threadIdx.x;
    int v = (tid < nb) ? bsum[tid] : 0;
    tmp[tid] = v;
    __syncthreads();
    for (int off = 1; off < 256; off <<= 1) {
        int t = (tid >= off) ? tmp[tid - off] : 0;
        __syncthreads();
        tmp[tid] += t;
        __syncthreads();
    }
    if (tid < nb) bsum[tid] = tmp[tid] - v;
    if (tid == 255) start[n] = tmp[255];
}

__global__ __launch_bounds__(256) void scan3(int* __restrict__ start, int* __restrict__ cursor,
                                             const int* __restrict__ bsum, int n) {
    int off = bsum[blockIdx.x];
    int base = blockIdx.x * 1024 + threadIdx.x * 4;
#pragma unroll
    for (int i = 0; i < 4; ++i) {
        int j = base + i;
        if (j < n) { int v = start[j] + off; start[j] = v; cursor[j] = v; }
    }
}

// ---------------- CSR build: scatter source rows, sorted by col ----------------
__global__ void build_kernel(const int* __restrict__ row, const int* __restrict__ col,
                             int* __restrict__ cursor, int* __restrict__ srcrow, int E) {
    int e = blockIdx.x * blockDim.x + threadIdx.x;
    if (e >= E) return;
    int p = atomicAdd(&cursor[col[e]], 1);
    srcrow[p] = row[e];
}

// ---------------- graph boundaries from sorted batch: gstart[65] ----------------
__global__ void gbound_kernel(const int* __restrict__ batch, int* __restrict__ gstart, int n) {
    int i = blockIdx.x * blockDim.x + threadIdx.x;
    if (i >= n) return;
    int b = batch[i];
    int prev = (i == 0) ? -1 : batch[i - 1];
    for (int g = prev + 1; g <= b; ++g) gstart[g] = i;
    if (i == n - 1) {
        for (int g = b + 1; g <= NUM_GRAPHS; ++g) gstart[g] = n;
    }
}

// ---------------- GEMM: C[M x 128] = A[M x 128] @ W[128 x 128], f64 accumulate ----------------
// As f64 (16.9 KB), Ws f32 (16.5 KB, exact cvt at read). Optional per-row output
// scale (dinv_r prefold for agg) or leaky activation (never both).
__global__ __launch_bounds__(256, 4) void gemm128_d(const float* __restrict__ A,
                                                    const float* __restrict__ W,
                                                    float* __restrict__ C, int M, int act,
                                                    const double* __restrict__ scale) {
    __shared__ double As[64][33];
    __shared__ float  Ws[32][129];
    const int tid = threadIdx.x;
    const int rg = tid >> 4;
    const int cg = tid & 15;
    const int rowBase = blockIdx.x * 64;

    double acc[4][8];
#pragma unroll
    for (int r = 0; r < 4; ++r)
#pragma unroll
        for (int j = 0; j < 8; ++j) acc[r][j] = 0.0;

    const int lr = tid >> 2;            // 0..63  A stage row
    const int lc = (tid & 3) * 8;       // 0,8,16,24
    const int wr = tid & 31;            // 0..31  W stage row (within chunk)
    const int wc = (tid >> 5) * 16;     // 0..112

    const int growA = rowBase + lr;
    const bool haveA = (growA < M);

    float4 a0 = make_float4(0.f, 0.f, 0.f, 0.f), a1 = a0;
    if (haveA) {
        const float4* src = reinterpret_cast<const float4*>(A + (size_t)growA * D + 0 + lc);
        a0 = src[0]; a1 = src[1];
    }

    for (int kc = 0; kc < 128; kc += 32) {
        *reinterpret_cast<double2*>(&As[lr][lc + 0]) = make_double2((double)a0.x, (double)a0.y);
        *reinterpret_cast<double2*>(&As[lr][lc + 2]) = make_double2((double)a0.z, (double)a0.w);
        *reinterpret_cast<double2*>(&As[lr][lc + 4]) = make_double2((double)a1.x, (double)a1.y);
        *reinterpret_cast<double2*>(&As[lr][lc + 6]) = make_double2((double)a1.z, (double)a1.w);
        {
            const float4* src = reinterpret_cast<const float4*>(W + (size_t)(kc + wr) * D + wc);
#pragma unroll
            for (int i = 0; i < 4; ++i)
                *reinterpret_cast<float4*>(&Ws[wr][wc + 4 * i]) = src[i];
        }
        __syncthreads();

        if (kc + 32 < 128 && haveA) {
            const float4* src = reinterpret_cast<const float4*>(A + (size_t)growA * D + (kc + 32) + lc);
            a0 = src[0]; a1 = src[1];
        }

#pragma unroll
        for (int k = 0; k < 32; ++k) {
            double xv0 = As[rg * 4 + 0][k];
            double xv1 = As[rg * 4 + 1][k];
            double xv2 = As[rg * 4 + 2][k];
            double xv3 = As[rg * 4 + 3][k];
            double w0 = (double)Ws[k][cg +   0];
            double w1 = (double)Ws[k][cg +  16];
            double w2 = (double)Ws[k][cg +  32];
            double w3 = (double)Ws[k][cg +  48];
            double w4 = (double)Ws[k][cg +  64];
            double w5 = (double)Ws[k][cg +  80];
            double w6 = (double)Ws[k][cg +  96];
            double w7 = (double)Ws[k][cg + 112];
            acc[0][0] = fma(xv0, w0, acc[0][0]); acc[0][1] = fma(xv0, w1, acc[0][1]);
            acc[0][2] = fma(xv0, w2, acc[0][2]); acc[0][3] = fma(xv0, w3, acc[0][3]);
            acc[0][4] = fma(xv0, w4, acc[0][4]); acc[0][5] = fma(xv0, w5, acc[0][5]);
            acc[0][6] = fma(xv0, w6, acc[0][6]); acc[0][7] = fma(xv0, w7, acc[0][7]);
            acc[1][0] = fma(xv1, w0, acc[1][0]); acc[1][1] = fma(xv1, w1, acc[1][1]);
            acc[1][2] = fma(xv1, w2, acc[1][2]); acc[1][3] = fma(xv1, w3, acc[1][3]);
            acc[1][4] = fma(xv1, w4, acc[1][4]); acc[1][5] = fma(xv1, w5, acc[1][5]);
            acc[1][6] = fma(xv1, w6, acc[1][6]); acc[1][7] = fma(xv1, w7, acc[1][7]);
            acc[2][0] = fma(xv2, w0, acc[2][0]); acc[2][1] = fma(xv2, w1, acc[2][1]);
            acc[2][2] = fma(xv2, w2, acc[2][2]); acc[2][3] = fma(xv2, w3, acc[2][3]);
            acc[2][4] = fma(xv2, w4, acc[2][4]); acc[2][5] = fma(xv2, w5, acc[2][5]);
            acc[2][6] = fma(xv2, w6, acc[2][6]); acc[2][7] = fma(xv2, w7, acc[2][7]);
            acc[3][0] = fma(xv3, w0, acc[3][0]); acc[3][1] = fma(xv3, w1, acc[3][1]);
            acc[3][2] = fma(xv3, w2, acc[3][2]); acc[3][3] = fma(xv3, w3, acc[3][3]);
            acc[3][4] = fma(xv3, w4, acc[3][4]); acc[3][5] = fma(xv3, w5, acc[3][5]);
            acc[3][6] = fma(xv3, w6, acc[3][6]); acc[3][7] = fma(xv3, w7, acc[3][7]);
        }
        __syncthreads();
    }

#pragma unroll
    for (int r = 0; r < 4; ++r) {
        int grow = rowBase + rg * 4 + r;
        if (grow < M) {
            double sc = scale ? scale[grow] : 1.0;
#pragma unroll
            for (int j = 0; j < 8; ++j) {
                double v = acc[r][j];
                if (act) v = dleaky(v);
                v *= sc;
                C[(size_t)grow * D + cg + 16 * j] = (float)v;
            }
        }
    }
}

// ---------------- aggregation over prescaled rows h' = dinv_r * h ----------------
// out[c] = leaky(dinv_c * (sum_edges h'[r] + h'[c])); 16-deep gather, chain idx->h'.
__global__ __launch_bounds__(256) void agg_s(const float* __restrict__ hp,
                                             const int* __restrict__ srcrow,
                                             const int* __restrict__ start,
                                             const double* __restrict__ dinvd,
                                             float* __restrict__ out, int n) {
    int node = (int)((blockIdx.x * blockDim.x + threadIdx.x) >> 6);
    int lane = threadIdx.x & 63;
    if (node >= n) return;
    int s = start[node], e = start[node + 1];
    double dn = dinvd[node];
    const int f = lane * 2;
    float2 hs = *reinterpret_cast<const float2*>(hp + (size_t)node * D + f);  // self row, early
    double ax = 0.0, ay = 0.0;
    int p = s;
    for (; p + 16 <= e; p += 16) {
        int r[16]; float2 hv[16];
#pragma unroll
        for (int i = 0; i < 16; ++i) r[i] = srcrow[p + i];
#pragma unroll
        for (int i = 0; i < 16; ++i)
            hv[i] = *reinterpret_cast<const float2*>(hp + (size_t)r[i] * D + f);
#pragma unroll
        for (int i = 0; i < 16; ++i) { ax += (double)hv[i].x; ay += (double)hv[i].y; }
    }
    for (; p + 8 <= e; p += 8) {
        int r[8]; float2 hv[8];
#pragma unroll
        for (int i = 0; i < 8; ++i) r[i] = srcrow[p + i];
#pragma unroll
        for (int i = 0; i < 8; ++i)
            hv[i] = *reinterpret_cast<const float2*>(hp + (size_t)r[i] * D + f);
#pragma unroll
        for (int i = 0; i < 8; ++i) { ax += (double)hv[i].x; ay += (double)hv[i].y; }
    }
    for (; p < e; ++p) {
        int r = srcrow[p];
        float2 hv = *reinterpret_cast<const float2*>(hp + (size_t)r * D + f);
        ax += (double)hv.x; ay += (double)hv.y;
    }
    ax = dleaky((ax + (double)hs.x) * dn);
    ay = dleaky((ay + (double)hs.y) * dn);
    *reinterpret_cast<float2*>(out + (size_t)node * D + f) =
        make_float2((float)ax, (float)ay);
}

// ---------------- fc2 (128->1): per-node scalar, f64 dot ----------------
__global__ __launch_bounds__(256) void fc2_d(const float* __restrict__ y,
                                             const float* __restrict__ w,
                                             double* __restrict__ s, int n) {
    int node = (int)((blockIdx.x * blockDim.x + threadIdx.x) >> 6);
    int lane = threadIdx.x & 63;
    if (node >= n) return;
    float2 yv = *reinterpret_cast<const float2*>(y + (size_t)node * D + lane * 2);
    float2 wv = *reinterpret_cast<const float2*>(w + lane * 2);
    double part = (double)yv.x * (double)wv.x + (double)yv.y * (double)wv.y;
#pragma unroll
    for (int off = 32; off > 0; off >>= 1) part += __shfl_down(part, off, 64);
    if (lane == 0) s[node] = dleaky(part);
}

// ---------------- pool: block per graph over its contiguous node range ----------------
__global__ __launch_bounds__(256) void pool2(const double* __restrict__ s,
                                             const int* __restrict__ gstart,
                                             float* __restrict__ out) {
    __shared__ double lsum[256];
    const int g = blockIdx.x;
    const int tid = threadIdx.x;
    const int s0 = gstart[g], s1 = gstart[g + 1];
    double sum = 0.0;
    for (int i = s0 + tid; i < s1; i += 256) sum += s[i];
    lsum[tid] = sum;
    __syncthreads();
    for (int off = 128; off > 0; off >>= 1) {
        if (tid < off) lsum[tid] += lsum[tid + off];
        __syncthreads();
    }
    if (tid == 0) {
        int cnt = s1 - s0;
        out[g] = (float)(lsum[0] / (double)(cnt > 0 ? cnt : 1));
    }
}

extern "C" void kernel_launch(void* const* d_in, const int* in_sizes, int n_in,
                              void* d_out, int out_size, void* d_ws, size_t ws_size,
                              hipStream_t stream) {
    const float* x    = (const float*)d_in[0];
    const int*   eidx = (const int*)d_in[1];
    const int*   batch= (const int*)d_in[2];
    const float* W0   = (const float*)d_in[3];
    const float* W1   = (const float*)d_in[4];
    const float* W2   = (const float*)d_in[5];
    const float* Wfc1 = (const float*)d_in[6];
    const float* Wfc2 = (const float*)d_in[7];
    float* out = (float*)d_out;

    const int* erow = eidx;
    const int* ecol = eidx + N_EDGES;

    char* ws = (char*)d_ws;
    int*    hist   = (int*)   (ws + 0);
    int*    start  = (int*)   (ws + 200064);
    int*    cursor = (int*)   (ws + 400384);   // dead after build -> reused as gstart
    int*    bsum   = (int*)   (ws + 600448);
    double* dinvd  = (double*)(ws + 600704);
    int*    srcrow = (int*)   (ws + 1000704);
    double* svec   = (double*)(ws + 4200704);
    float*  bufA   = (float*) (ws + 4600832);
    float*  bufB   = (float*) (ws + 30200832);
    int*    gstart = cursor;

    zero_kernel<<<(N_NODES + 255) / 256, 256, 0, stream>>>(hist, N_NODES);
    hist_kernel<<<(N_EDGES + 255) / 256, 256, 0, stream>>>(ecol, hist, N_EDGES);
    dinv_kernel<<<(N_NODES + 255) / 256, 256, 0, stream>>>(hist, dinvd, N_NODES);

    const int NB = (N_NODES + 1023) / 1024;  // 49
    scan1<<<NB, 256, 0, stream>>>(hist, start, bsum, N_NODES);
    scan2<<<1, 256, 0, stream>>>(bsum, NB, start, N_NODES);
    scan3<<<NB, 256, 0, stream>>>(start, cursor, bsum, N_NODES);

    build_kernel<<<(N_EDGES + 255) / 256, 256, 0, stream>>>(erow, ecol, cursor, srcrow, N_EDGES);
    gbound_kernel<<<(N_NODES + 255) / 256, 256, 0, stream>>>(batch, gstart, N_NODES);

    const int GEMM_GRID = (N_NODES + 63) / 64;   // 782
    const int AGG_GRID  = (N_NODES + 3) / 4;     // 12500

    // layers 0..2: gemm writes prescaled h' = dinv_r * (h @ W); agg_s finishes
    gemm128_d<<<GEMM_GRID, 256, 0, stream>>>(x, W0, bufA, N_NODES, 0, dinvd);
    agg_s<<<AGG_GRID, 256, 0, stream>>>(bufA, srcrow, start, dinvd, bufB, N_NODES);
    gemm128_d<<<GEMM_GRID, 256, 0, stream>>>(bufB, W1, bufA, N_NODES, 0, dinvd);
    agg_s<<<AGG_GRID, 256, 0, stream>>>(bufA, srcrow, start, dinvd, bufB, N_NODES);
    gemm128_d<<<GEMM_GRID, 256, 0, stream>>>(bufB, W2, bufA, N_NODES, 0, dinvd);
    agg_s<<<AGG_GRID, 256, 0, stream>>>(bufA, srcrow, start, dinvd, bufB, N_NODES);
    // fc1: plain leaky output
    gemm128_d<<<GEMM_GRID, 256, 0, stream>>>(bufB, Wfc1, bufA, N_NODES, 1, (const double*)nullptr);

    fc2_d<<<AGG_GRID, 256, 0, stream>>>(bufA, Wfc2, svec, N_NODES);
    pool2<<<NUM_GRAPHS, 256, 0, stream>>>(svec, gstart, out);
}

// Round 8
// 465.335 us; speedup vs baseline: 2.0261x; 1.0751x over previous
//
#include <hip/hip_runtime.h>

#define N_NODES   50000
#define N_EDGES   800000
#define NUM_GRAPHS 64
#define D         128
#define SLOPE     0.01

typedef double d4 __attribute__((ext_vector_type(4)));

__device__ __forceinline__ double dleaky(double v) { return v >= 0.0 ? v : SLOPE * v; }

// ---------------- zero ----------------
__global__ void zero_kernel(int* __restrict__ p, int n) {
    int i = blockIdx.x * blockDim.x + threadIdx.x;
    if (i < n) p[i] = 0;
}

// ---------------- degree histogram (by col) ----------------
__global__ void hist_kernel(const int* __restrict__ col, int* __restrict__ hist, int E) {
    int e = blockIdx.x * blockDim.x + threadIdx.x;
    if (e < E) atomicAdd(&hist[col[e]], 1);
}

// ---------------- dinv = 1/sqrt(deg+1) in double ----------------
__global__ void dinv_kernel(const int* __restrict__ hist, double* __restrict__ dinvd, int n) {
    int i = blockIdx.x * blockDim.x + threadIdx.x;
    if (i < n) dinvd[i] = 1.0 / sqrt((double)hist[i] + 1.0);
}

// ---------------- multi-block exclusive scan (3 kernels) ----------------
__global__ __launch_bounds__(256) void scan1(const int* __restrict__ hist,
                                             int* __restrict__ start,
                                             int* __restrict__ bsum, int n) {
    __shared__ int tmp[256];
    const int tid = threadIdx.x;
    int base = blockIdx.x * 1024 + tid * 4;
    int v[4]; int s = 0;
#pragma unroll
    for (int i = 0; i < 4; ++i) { int idx = base + i; v[i] = (idx < n) ? hist[idx] : 0; s += v[i]; }
    tmp[tid] = s;
    __syncthreads();
    for (int off = 1; off < 256; off <<= 1) {
        int t = (tid >= off) ? tmp[tid - off] : 0;
        __syncthreads();
        tmp[tid] += t;
        __syncthreads();
    }
    int run = tmp[tid] - s;
    if (tid == 255) bsum[blockIdx.x] = tmp[255];
#pragma unroll
    for (int i = 0; i < 4; ++i) { int idx = base + i; if (idx < n) start[idx] = run; run += v[i]; }
}

__global__ __launch_bounds__(256) void scan2(int* __restrict__ bsum, int nb,
                                             int* __restrict__ start, int n) {
    __shared__ int tmp[256];
    const int tid = threadIdx.x;
    int v = (tid < nb) ? bsum[tid] : 0;
    tmp[tid] = v;
    __syncthreads();
    for (int off = 1; off < 256; off <<= 1) {
        int t = (tid >= off) ? tmp[tid - off] : 0;
        __syncthreads();
        tmp[tid] += t;
        __syncthreads();
    }
    if (tid < nb) bsum[tid] = tmp[tid] - v;
    if (tid == 255) start[n] = tmp[255];
}

__global__ __launch_bounds__(256) void scan3(int* __restrict__ start, int* __restrict__ cursor,
                                             const int* __restrict__ bsum, int n) {
    int off = bsum[blockIdx.x];
    int base = blockIdx.x * 1024 + threadIdx.x * 4;
#pragma unroll
    for (int i = 0; i < 4; ++i) {
        int j = base + i;
        if (j < n) { int v = start[j] + off; start[j] = v; cursor[j] = v; }
    }
}

// ---------------- CSR build: scatter source rows, sorted by col ----------------
__global__ void build_kernel(const int* __restrict__ row, const int* __restrict__ col,
                             int* __restrict__ cursor, int* __restrict__ srcrow, int E) {
    int e = blockIdx.x * blockDim.x + threadIdx.x;
    if (e >= E) return;
    int p = atomicAdd(&cursor[col[e]], 1);
    srcrow[p] = row[e];
}

// ---------------- graph boundaries from sorted batch: gstart[65] ----------------
__global__ void gbound_kernel(const int* __restrict__ batch, int* __restrict__ gstart, int n) {
    int i = blockIdx.x * blockDim.x + threadIdx.x;
    if (i >= n) return;
    int b = batch[i];
    int prev = (i == 0) ? -1 : batch[i - 1];
    for (int g = prev + 1; g <= b; ++g) gstart[g] = i;
    if (i == n - 1) {
        for (int g = b + 1; g <= NUM_GRAPHS; ++g) gstart[g] = n;
    }
}

// ---------------- GEMM via v_mfma_f64_16x16x4: C = A @ W (f64 accumulate) ----------------
// Block tile 32 rows x 128 cols, 4 waves (2M x 2N), wave = 16 rows x 64 cols (4 MFMA tiles).
// As staged f64 (8.4 KB), Ws staged f32 (16.5 KB, exact cvt to f64 at frag read).
// MFMA layouts (gfx950 16x16 pattern): A: row=lane&15, k=lane>>4; B: col=lane&15,
// k=lane>>4; C/D: col=lane&15, row=4*(lane>>4)+reg.
__global__ __launch_bounds__(256, 4) void gemm128_mfma(const float* __restrict__ A,
                                                       const float* __restrict__ W,
                                                       float* __restrict__ C, int M, int act,
                                                       const double* __restrict__ scale) {
    __shared__ double As[32][33];
    __shared__ float  Ws[32][129];
    const int tid  = threadIdx.x;
    const int lane = tid & 63;
    const int wid  = tid >> 6;        // 0..3
    const int wrow = wid >> 1;        // 0..1: rows wrow*16..+15
    const int wcol = wid & 1;         // 0..1: cols wcol*64..+63
    const int rowBase = blockIdx.x * 32;

    d4 acc0 = {0.0, 0.0, 0.0, 0.0};
    d4 acc1 = {0.0, 0.0, 0.0, 0.0};
    d4 acc2 = {0.0, 0.0, 0.0, 0.0};
    d4 acc3 = {0.0, 0.0, 0.0, 0.0};

    // staging assignments
    const int lr = tid >> 3;          // 0..31 A row
    const int lc = (tid & 7) * 4;     // 0..28 A cols (4 per thread)
    const int wr = tid & 31;          // 0..31 W row in chunk
    const int wc = (tid >> 5) * 16;   // 0..112 W cols (16 per thread)

    const int growA = rowBase + lr;
    const bool haveA = (growA < M);

    float4 a0 = make_float4(0.f, 0.f, 0.f, 0.f);
    if (haveA) a0 = *reinterpret_cast<const float4*>(A + (size_t)growA * D + lc);

    const int arow = wrow * 16 + (lane & 15);
    const int asub = lane >> 4;       // k sub-index 0..3
    const int bcol = wcol * 64 + (lane & 15);

    for (int kc = 0; kc < 128; kc += 32) {
        As[lr][lc + 0] = (double)a0.x;
        As[lr][lc + 1] = (double)a0.y;
        As[lr][lc + 2] = (double)a0.z;
        As[lr][lc + 3] = (double)a0.w;
        {
            const float4* src = reinterpret_cast<const float4*>(W + (size_t)(kc + wr) * D + wc);
#pragma unroll
            for (int i = 0; i < 4; ++i)
                *reinterpret_cast<float4*>(&Ws[wr][wc + 4 * i]) = src[i];
        }
        __syncthreads();

        if (kc + 32 < 128 && haveA)
            a0 = *reinterpret_cast<const float4*>(A + (size_t)growA * D + (kc + 32) + lc);

#pragma unroll
        for (int kk = 0; kk < 8; ++kk) {
            double av = As[arow][kk * 4 + asub];
            double b0 = (double)Ws[kk * 4 + asub][bcol +  0];
            double b1 = (double)Ws[kk * 4 + asub][bcol + 16];
            double b2 = (double)Ws[kk * 4 + asub][bcol + 32];
            double b3 = (double)Ws[kk * 4 + asub][bcol + 48];
            acc0 = __builtin_amdgcn_mfma_f64_16x16x4f64(av, b0, acc0, 0, 0, 0);
            acc1 = __builtin_amdgcn_mfma_f64_16x16x4f64(av, b1, acc1, 0, 0, 0);
            acc2 = __builtin_amdgcn_mfma_f64_16x16x4f64(av, b2, acc2, 0, 0, 0);
            acc3 = __builtin_amdgcn_mfma_f64_16x16x4f64(av, b3, acc3, 0, 0, 0);
        }
        __syncthreads();
    }

    // epilogue: reg r of tile t -> row rbase+r, col wcol*64 + t*16 + (lane&15)
    const int rbase = rowBase + wrow * 16 + 4 * (lane >> 4);
    const int cb = wcol * 64 + (lane & 15);
#pragma unroll
    for (int r = 0; r < 4; ++r) {
        int grow = rbase + r;
        if (grow < M) {
            double sc = scale ? scale[grow] : 1.0;
            double v0 = acc0[r], v1 = acc1[r], v2 = acc2[r], v3 = acc3[r];
            if (act) { v0 = dleaky(v0); v1 = dleaky(v1); v2 = dleaky(v2); v3 = dleaky(v3); }
            v0 *= sc; v1 *= sc; v2 *= sc; v3 *= sc;
            float* crow = C + (size_t)grow * D + cb;
            crow[ 0] = (float)v0;
            crow[16] = (float)v1;
            crow[32] = (float)v2;
            crow[48] = (float)v3;
        }
    }
}

// ---------------- aggregation over prescaled rows h' = dinv_r * h ----------------
__global__ __launch_bounds__(256) void agg_s(const float* __restrict__ hp,
                                             const int* __restrict__ srcrow,
                                             const int* __restrict__ start,
                                             const double* __restrict__ dinvd,
                                             float* __restrict__ out, int n) {
    int node = (int)((blockIdx.x * blockDim.x + threadIdx.x) >> 6);
    int lane = threadIdx.x & 63;
    if (node >= n) return;
    int s = start[node], e = start[node + 1];
    double dn = dinvd[node];
    const int f = lane * 2;
    float2 hs = *reinterpret_cast<const float2*>(hp + (size_t)node * D + f);
    double ax = 0.0, ay = 0.0;
    int p = s;
    for (; p + 16 <= e; p += 16) {
        int r[16]; float2 hv[16];
#pragma unroll
        for (int i = 0; i < 16; ++i) r[i] = srcrow[p + i];
#pragma unroll
        for (int i = 0; i < 16; ++i)
            hv[i] = *reinterpret_cast<const float2*>(hp + (size_t)r[i] * D + f);
#pragma unroll
        for (int i = 0; i < 16; ++i) { ax += (double)hv[i].x; ay += (double)hv[i].y; }
    }
    for (; p + 8 <= e; p += 8) {
        int r[8]; float2 hv[8];
#pragma unroll
        for (int i = 0; i < 8; ++i) r[i] = srcrow[p + i];
#pragma unroll
        for (int i = 0; i < 8; ++i)
            hv[i] = *reinterpret_cast<const float2*>(hp + (size_t)r[i] * D + f);
#pragma unroll
        for (int i = 0; i < 8; ++i) { ax += (double)hv[i].x; ay += (double)hv[i].y; }
    }
    for (; p < e; ++p) {
        int r = srcrow[p];
        float2 hv = *reinterpret_cast<const float2*>(hp + (size_t)r * D + f);
        ax += (double)hv.x; ay += (double)hv.y;
    }
    ax = dleaky((ax + (double)hs.x) * dn);
    ay = dleaky((ay + (double)hs.y) * dn);
    *reinterpret_cast<float2*>(out + (size_t)node * D + f) =
        make_float2((float)ax, (float)ay);
}

// ---------------- fc2 (128->1): per-node scalar, f64 dot ----------------
__global__ __launch_bounds__(256) void fc2_d(const float* __restrict__ y,
                                             const float* __restrict__ w,
                                             double* __restrict__ s, int n) {
    int node = (int)((blockIdx.x * blockDim.x + threadIdx.x) >> 6);
    int lane = threadIdx.x & 63;
    if (node >= n) return;
    float2 yv = *reinterpret_cast<const float2*>(y + (size_t)node * D + lane * 2);
    float2 wv = *reinterpret_cast<const float2*>(w + lane * 2);
    double part = (double)yv.x * (double)wv.x + (double)yv.y * (double)wv.y;
#pragma unroll
    for (int off = 32; off > 0; off >>= 1) part += __shfl_down(part, off, 64);
    if (lane == 0) s[node] = dleaky(part);
}

// ---------------- pool: block per graph over its contiguous node range ----------------
__global__ __launch_bounds__(256) void pool2(const double* __restrict__ s,
                                             const int* __restrict__ gstart,
                                             float* __restrict__ out) {
    __shared__ double lsum[256];
    const int g = blockIdx.x;
    const int tid = threadIdx.x;
    const int s0 = gstart[g], s1 = gstart[g + 1];
    double sum = 0.0;
    for (int i = s0 + tid; i < s1; i += 256) sum += s[i];
    lsum[tid] = sum;
    __syncthreads();
    for (int off = 128; off > 0; off >>= 1) {
        if (tid < off) lsum[tid] += lsum[tid + off];
        __syncthreads();
    }
    if (tid == 0) {
        int cnt = s1 - s0;
        out[g] = (float)(lsum[0] / (double)(cnt > 0 ? cnt : 1));
    }
}

extern "C" void kernel_launch(void* const* d_in, const int* in_sizes, int n_in,
                              void* d_out, int out_size, void* d_ws, size_t ws_size,
                              hipStream_t stream) {
    const float* x    = (const float*)d_in[0];
    const int*   eidx = (const int*)d_in[1];
    const int*   batch= (const int*)d_in[2];
    const float* W0   = (const float*)d_in[3];
    const float* W1   = (const float*)d_in[4];
    const float* W2   = (const float*)d_in[5];
    const float* Wfc1 = (const float*)d_in[6];
    const float* Wfc2 = (const float*)d_in[7];
    float* out = (float*)d_out;

    const int* erow = eidx;
    const int* ecol = eidx + N_EDGES;

    char* ws = (char*)d_ws;
    int*    hist   = (int*)   (ws + 0);
    int*    start  = (int*)   (ws + 200064);
    int*    cursor = (int*)   (ws + 400384);   // dead after build -> reused as gstart
    int*    bsum   = (int*)   (ws + 600448);
    double* dinvd  = (double*)(ws + 600704);
    int*    srcrow = (int*)   (ws + 1000704);
    double* svec   = (double*)(ws + 4200704);
    float*  bufA   = (float*) (ws + 4600832);
    float*  bufB   = (float*) (ws + 30200832);
    int*    gstart = cursor;

    zero_kernel<<<(N_NODES + 255) / 256, 256, 0, stream>>>(hist, N_NODES);
    hist_kernel<<<(N_EDGES + 255) / 256, 256, 0, stream>>>(ecol, hist, N_EDGES);
    dinv_kernel<<<(N_NODES + 255) / 256, 256, 0, stream>>>(hist, dinvd, N_NODES);

    const int NB = (N_NODES + 1023) / 1024;  // 49
    scan1<<<NB, 256, 0, stream>>>(hist, start, bsum, N_NODES);
    scan2<<<1, 256, 0, stream>>>(bsum, NB, start, N_NODES);
    scan3<<<NB, 256, 0, stream>>>(start, cursor, bsum, N_NODES);

    build_kernel<<<(N_EDGES + 255) / 256, 256, 0, stream>>>(erow, ecol, cursor, srcrow, N_EDGES);
    gbound_kernel<<<(N_NODES + 255) / 256, 256, 0, stream>>>(batch, gstart, N_NODES);

    const int GEMM_GRID = (N_NODES + 31) / 32;   // 1563
    const int AGG_GRID  = (N_NODES + 3) / 4;     // 12500

    // layers 0..2: gemm writes prescaled h' = dinv_r * (h @ W); agg_s finishes
    gemm128_mfma<<<GEMM_GRID, 256, 0, stream>>>(x, W0, bufA, N_NODES, 0, dinvd);
    agg_s<<<AGG_GRID, 256, 0, stream>>>(bufA, srcrow, start, dinvd, bufB, N_NODES);
    gemm128_mfma<<<GEMM_GRID, 256, 0, stream>>>(bufB, W1, bufA, N_NODES, 0, dinvd);
    agg_s<<<AGG_GRID, 256, 0, stream>>>(bufA, srcrow, start, dinvd, bufB, N_NODES);
    gemm128_mfma<<<GEMM_GRID, 256, 0, stream>>>(bufB, W2, bufA, N_NODES, 0, dinvd);
    agg_s<<<AGG_GRID, 256, 0, stream>>>(bufA, srcrow, start, dinvd, bufB, N_NODES);
    // fc1: plain leaky output
    gemm128_mfma<<<GEMM_GRID, 256, 0, stream>>>(bufB, Wfc1, bufA, N_NODES, 1, (const double*)nullptr);

    fc2_d<<<AGG_GRID, 256, 0, stream>>>(bufA, Wfc2, svec, N_NODES);
    pool2<<<NUM_GRAPHS, 256, 0, stream>>>(svec, gstart, out);
}